// Round 12
// baseline (482.176 us; speedup 1.0000x reference)
//
#include <hip/hip_runtime.h>
#include <hip/hip_bf16.h>

typedef unsigned short u16;
typedef __bf16 bf16x8 __attribute__((ext_vector_type(8)));
typedef float f32x4 __attribute__((ext_vector_type(4)));

#define B_IMG 128
#define NOBJ  36
#define NNODE (B_IMG * NOBJ)

__device__ __forceinline__ float b2f(u16 u) {
    union { unsigned int i; float f; } v; v.i = ((unsigned int)u) << 16; return v.f;
}
__device__ __forceinline__ u16 f2b(float f) {
    union { float f; unsigned int i; } v; v.f = f;
    unsigned int u = v.i;
    return (u16)((u + 0x7fffu + ((u >> 16) & 1u)) >> 16);   // RNE
}

// ---------------------------------------------------------------------------
// 64x64 convert+transpose tile body: src [Rs, C] fp32 -> dst [C, Rd] bf16,
// rows k >= Rs zero-filled.  Reads 256 B/instr, writes 128 B/instr.
// ---------------------------------------------------------------------------
__device__ __forceinline__ void tr64_body(u16 (*tile)[65], const float* __restrict__ src,
                                          u16* __restrict__ dst, int Rs, int Rd, int C,
                                          int tb, int t)
{
    const int ntx = C >> 6;
    const int ty = tb / ntx, tx = tb - ty * ntx;
    const int bx = tx * 64, by = ty * 64;     // bx: src col / dst row; by: src row (k)
    const int x = t & 63, y = t >> 6;         // 64 x 4
    #pragma unroll
    for (int i = y; i < 64; i += 4) {
        const int k = by + i;
        tile[i][x] = (k < Rs) ? f2b(src[(size_t)k * C + bx + x]) : (u16)0;
    }
    __syncthreads();
    #pragma unroll
    for (int i = y; i < 64; i += 4)
        dst[(size_t)(bx + i) * Rd + by + x] = tile[x][i];
}

// ---------------------------------------------------------------------------
// Fused S0 prep (one launch): of pack | qe pad | WqT | WvT | W3T | W1T | W2T.
// Block ranges: [0,9216) of | [+1280) qe | [+1280) Wq | [+1024) Wv |
// [+640) W3 | [+512) W1 | [+256) W2.   Total 14208.
// ---------------------------------------------------------------------------
__global__ __launch_bounds__(256)
void prep_all(const float* __restrict__ of, u16* __restrict__ of_c,
              const float* __restrict__ qe, u16* __restrict__ qe_c,
              const float* __restrict__ Wq, u16* __restrict__ WqT,
              const float* __restrict__ Wv, u16* __restrict__ WvT,
              const float* __restrict__ W3, u16* __restrict__ W3T,
              const float* __restrict__ W1, u16* __restrict__ W1T,
              const float* __restrict__ W2, u16* __restrict__ W2T)
{
    __shared__ u16 tile[64][65];
    int b = blockIdx.x;
    const int t = threadIdx.x;
    if (b < 9216) {
        const int i = b * 256 + t;               // < 4608*2048/4 exactly
        const float4 f = ((const float4*)of)[i];
        ushort4 o; o.x = f2b(f.x); o.y = f2b(f.y); o.z = f2b(f.z); o.w = f2b(f.w);
        ((ushort4*)of_c)[i] = o;
        return;
    }
    b -= 9216;
    if (b < 1280) {
        const int i = b * 256 + t;               // < 128*2560 exactly
        const int r = i / 2560, c = i - r * 2560;
        qe_c[i] = (c < 2400) ? f2b(qe[r * 2400 + c]) : (u16)0;
        return;
    }
    b -= 1280;
    if (b < 1280) { tr64_body(tile, Wq, WqT, 2400, 2560, 2048, b, t); return; }
    b -= 1280;
    if (b < 1024) { tr64_body(tile, Wv, WvT, 2048, 2048, 2048, b, t); return; }
    b -= 1024;
    if (b < 640)  { tr64_body(tile, W3, W3T, 1024, 1024, 2560, b, t); return; }
    b -= 640;
    if (b < 512)  { tr64_body(tile, W1, W1T, 2048, 2048, 1024, b, t); return; }
    b -= 512;
    tr64_body(tile, W2, W2T, 1024, 1024, 1024, b, t);
}

// ---------------------------------------------------------------------------
// TN MFMA GEMM: C[M,N] = A[M,K] * Bt[N,K]^T   (bf16 in, fp32 acc)
// Frozen r7 schedule (2-stage, vmcnt(0)+barrier/iter, XCD swizzle) with a
// BM parameter.  BM=128: 4x4 frags/wave, 32 KB LDS, 4 blocks/CU (S4/S11,
// grids >= 576).  BM=64: 2x4 frags/wave, 24 KB LDS, 6 blocks/CU — for the
// grid-starved shapes (S6/S8 were 288 blocks = 1.125/CU; at BM=64 they get
// 576 blocks + 6-deep residency to overlap the vmcnt drains, the measured
// mechanism behind r0's BK 64->32 win).
// EPI: 1 = splitK fp32 partial, 2 = +bias then *qmul -> bf16, 0 = bf16.
// ---------------------------------------------------------------------------
template<int EPI, int BM>
__global__ __launch_bounds__(256, (BM == 64 ? 6 : 4))
void gemm_tn(const u16* __restrict__ A, const u16* __restrict__ Bt,
             int M, int N, int K, int kLen,
             float* __restrict__ Cf, u16* __restrict__ Cb,
             const float* __restrict__ bias, const float* __restrict__ qmul)
{
    constexpr int RF  = BM / 32;          // row frags per wave (wr covers RF*16 rows)
    constexpr int ASZ = BM * 32;          // A stage size in u16
    constexpr int SS  = ASZ + 4096;       // stage stride in u16
    __shared__ __align__(16) u16 lds[2 * SS];

    const int t    = threadIdx.x;
    const int lane = t & 63;
    const int wave = t >> 6;
    const int wr = wave >> 1, wc = wave & 1;
    const int quad = lane >> 4, l16 = lane & 15;

    // XCD swizzle: contiguous chunk of the xy-grid per XCD (bijective: nxy%8==0)
    const int nxy = gridDim.x * gridDim.y;
    int bid = blockIdx.x + gridDim.x * blockIdx.y;
    const int cpx = nxy >> 3;
    bid = (bid & 7) * cpx + (bid >> 3);
    const int bx = bid % gridDim.x, by = bid / gridDim.x;

    const int rowBase = by * BM;
    const int colBase = bx * 128;
    const int k0 = blockIdx.z * kLen;

    // staging: wave w owns A rows [w*(BM/4), +BM/4) (1 or 2 x 16-row DMA)
    // and B rows [w*32, +32) (2 x 16-row DMA).
    const u16* gA0 = A  + (size_t)(rowBase + wave * (BM / 4) + (lane >> 2)) * K + k0 + (lane & 3) * 8;
    const u16* gA1 = gA0 + 16 * (size_t)K;
    const u16* gB0 = Bt + (size_t)(colBase + wave * 32 + (lane >> 2)) * K + k0 + (lane & 3) * 8;
    const u16* gB1 = gB0 + 16 * (size_t)K;
    const int roA = wave * (BM / 4) * 32;
    const int roB = wave * 1024;

    int afr[RF], bfr[4];
    #pragma unroll
    for (int r = 0; r < RF; r++) afr[r] = (wr * (RF * 16) + r * 16 + l16) * 32 + quad * 8;
    #pragma unroll
    for (int c = 0; c < 4; c++) bfr[c] = ASZ + (wc * 64 + c * 16 + l16) * 32 + quad * 8;

    f32x4 acc[RF][4];
    #pragma unroll
    for (int r = 0; r < RF; r++)
        #pragma unroll
        for (int c = 0; c < 4; c++)
            acc[r][c] = (f32x4){0.f, 0.f, 0.f, 0.f};

    auto gld = [](const u16* g, u16* s) {
        __builtin_amdgcn_global_load_lds(
            (const __attribute__((address_space(1))) void*)g,
            (__attribute__((address_space(3))) void*)s, 16, 0, 0);
    };
    auto dma_stage = [&](int it, int st) {
        const int kk = it * 32;
        const int bo = st * SS;
        gld(gA0 + kk, &lds[bo + roA]);
        if constexpr (BM == 128) gld(gA1 + kk, &lds[bo + roA + 512]);
        gld(gB0 + kk, &lds[bo + ASZ + roB]);
        gld(gB1 + kk, &lds[bo + ASZ + roB + 512]);
    };

    const int nIter = kLen >> 5;   // kLen % 32 == 0 at all call sites
    dma_stage(0, 0);

    for (int it = 0; it < nIter; ++it) {
        asm volatile("s_waitcnt vmcnt(0)\n\ts_barrier" ::: "memory");
        if (it + 1 < nIter) dma_stage(it + 1, (it + 1) & 1);
        const int bo = (it & 1) * SS;
        bf16x8 avf[RF], bvf[4];
        #pragma unroll
        for (int r = 0; r < RF; r++) avf[r] = *(const bf16x8*)&lds[bo + afr[r]];
        #pragma unroll
        for (int c = 0; c < 4; c++) bvf[c] = *(const bf16x8*)&lds[bo + bfr[c]];
        #pragma unroll
        for (int r = 0; r < RF; r++)
            #pragma unroll
            for (int c = 0; c < 4; c++)
                acc[r][c] = __builtin_amdgcn_mfma_f32_16x16x32_bf16(avf[r], bvf[c], acc[r][c], 0, 0, 0);
    }

    // epilogue: D row = quad*4+reg, col = l16
    #pragma unroll
    for (int r = 0; r < RF; r++) {
        const int mBase = rowBase + wr * (RF * 16) + r * 16 + quad * 4;
        #pragma unroll
        for (int c = 0; c < 4; c++) {
            const int n = colBase + wc * 64 + c * 16 + l16;
            #pragma unroll
            for (int e = 0; e < 4; e++) {
                const int m = mBase + e;
                float v = acc[r][c][e];
                if (EPI == 1) {
                    Cf[((size_t)blockIdx.z * M + m) * N + n] = v;
                } else if (EPI == 2) {
                    v += bias[n];
                    v *= qmul[(size_t)(m / NOBJ) * N + n];
                    Cb[(size_t)m * N + n] = f2b(v);
                } else {
                    Cb[(size_t)m * N + n] = f2b(v);
                }
            }
        }
    }
}

// ---------------------------------------------------------------------------
__global__ __launch_bounds__(256)
void qcombine(const float* __restrict__ p, const float* __restrict__ bias,
              float* __restrict__ q, int MN, int S)
{
    const int i = blockIdx.x * 256 + threadIdx.x;
    float s = 0.f;
    for (int z = 0; z < S; z++) s += p[(size_t)z * MN + i];
    q[i] = s + bias[i & 2047];
}

// ---------------------------------------------------------------------------
// Fused attention per (image, head) — layers 1/2 (r10: uint4 hl reads).
// MODE 1: relu(agg+b) -> g (bf16);  MODE 2: relu(agg+b)+resid -> g
// ---------------------------------------------------------------------------
template<int H, int C, int MODE>
__global__ __launch_bounds__(256)
void attn_kernel(const u16* __restrict__ h, const float* __restrict__ a_src,
                 const float* __restrict__ a_dst, const float* __restrict__ bias,
                 const u16* __restrict__ resid, u16* __restrict__ outb)
{
    __shared__ __align__(16) u16 hl[36 * C];
    __shared__ float alpha[36 * 36];
    __shared__ float asl[36], adl[36];
    __shared__ float psum[36][8][2];
    const int b = blockIdx.y, hd = blockIdx.x;
    const int t = threadIdx.x;
    const int nb = b * NOBJ;
    constexpr int CH = C / 8;
    for (int e = t; e < 36 * CH; e += 256) {
        const int row = e / CH, col = (e - row * CH) * 8;
        *(uint4*)&hl[row * C + col] = *(const uint4*)&h[(size_t)(nb + row) * (H * C) + hd * C + col];
    }
    __syncthreads();
    constexpr int SEG = C / 8;
    for (int e = t; e < 36 * 8; e += 256) {
        const int n = e >> 3, sg = e & 7;
        const u16*   hp = &hl[n * C + sg * SEG];
        const float* as = a_src + hd * C + sg * SEG;
        const float* ad = a_dst + hd * C + sg * SEG;
        float s1 = 0.f, s2 = 0.f;
        #pragma unroll 8
        for (int i = 0; i < SEG; i++) {
            const float hv = b2f(hp[i]);
            s1 += hv * as[i]; s2 += hv * ad[i];
        }
        psum[n][sg][0] = s1; psum[n][sg][1] = s2;
    }
    __syncthreads();
    if (t < 36) {
        float s1 = 0.f, s2 = 0.f;
        #pragma unroll
        for (int sg = 0; sg < 8; sg++) { s1 += psum[t][sg][0]; s2 += psum[t][sg][1]; }
        asl[t] = s1; adl[t] = s2;
    }
    __syncthreads();
    if (t < 36) {
        const float ad = adl[t];
        float mx = -1e30f;
        for (int s = 0; s < 36; s++) {
            float v = asl[s] + ad; v = (v > 0.f) ? v : 0.2f * v;
            alpha[t * 36 + s] = v; mx = fmaxf(mx, v);
        }
        float sum = 0.f;
        for (int s = 0; s < 36; s++) { const float ex = expf(alpha[t * 36 + s] - mx); alpha[t * 36 + s] = ex; sum += ex; }
        const float inv = 1.f / (sum + 1e-16f);
        for (int s = 0; s < 36; s++) alpha[t * 36 + s] *= inv;
    }
    __syncthreads();
    constexpr int NC8 = C / 8;
    for (int e = t; e < 36 * NC8; e += 256) {
        const int d = e / NC8, c8 = (e - d * NC8) * 8;
        float a0 = 0, a1 = 0, a2 = 0, a3 = 0, a4 = 0, a5 = 0, a6 = 0, a7 = 0;
        for (int s = 0; s < 36; s++) {
            const float al = alpha[d * 36 + s];
            const uint4 hv = *(const uint4*)&hl[s * C + c8];
            a0 += al * b2f((u16)hv.x);  a1 += al * b2f((u16)(hv.x >> 16));
            a2 += al * b2f((u16)hv.y);  a3 += al * b2f((u16)(hv.y >> 16));
            a4 += al * b2f((u16)hv.z);  a5 += al * b2f((u16)(hv.z >> 16));
            a6 += al * b2f((u16)hv.w);  a7 += al * b2f((u16)(hv.w >> 16));
        }
        const int n = nb + d;
        const size_t base = (size_t)n * (H * C) + hd * C + c8;
        const int bb = hd * C + c8;
        float v0 = a0 + bias[bb + 0], v1 = a1 + bias[bb + 1];
        float v2 = a2 + bias[bb + 2], v3 = a3 + bias[bb + 3];
        float v4 = a4 + bias[bb + 4], v5 = a5 + bias[bb + 5];
        float v6 = a6 + bias[bb + 6], v7 = a7 + bias[bb + 7];
        v0 = v0 > 0.f ? v0 : 0.f; v1 = v1 > 0.f ? v1 : 0.f;
        v2 = v2 > 0.f ? v2 : 0.f; v3 = v3 > 0.f ? v3 : 0.f;
        v4 = v4 > 0.f ? v4 : 0.f; v5 = v5 > 0.f ? v5 : 0.f;
        v6 = v6 > 0.f ? v6 : 0.f; v7 = v7 > 0.f ? v7 : 0.f;
        if (MODE == 2) {
            const uint4 rv = *(const uint4*)&resid[base];
            v0 += b2f((u16)rv.x); v1 += b2f((u16)(rv.x >> 16));
            v2 += b2f((u16)rv.y); v3 += b2f((u16)(rv.y >> 16));
            v4 += b2f((u16)rv.z); v5 += b2f((u16)(rv.z >> 16));
            v6 += b2f((u16)rv.w); v7 += b2f((u16)(rv.w >> 16));
        }
        uint4 ov;
        ov.x = (unsigned)f2b(v0) | ((unsigned)f2b(v1) << 16);
        ov.y = (unsigned)f2b(v2) | ((unsigned)f2b(v3) << 16);
        ov.z = (unsigned)f2b(v4) | ((unsigned)f2b(v5) << 16);
        ov.w = (unsigned)f2b(v6) | ((unsigned)f2b(v7) << 16);
        *(uint4*)&outb[base] = ov;
    }
}

// ---------------------------------------------------------------------------
// Fused al + softmax per (head, image), layer 3 -> alphaG (0.2 mean folded).
// ---------------------------------------------------------------------------
template<int H, int C, bool MEAN>
__global__ __launch_bounds__(256)
void al_alpha(const u16* __restrict__ h, const float* __restrict__ a_s,
              const float* __restrict__ a_d, float* __restrict__ alphaG)
{
    __shared__ float asl[36], adl[36];
    const int hd = blockIdx.x, b = blockIdx.y;
    const int nb = b * NOBJ;
    const int t = threadIdx.x, wv = t >> 6, lane = t & 63;
    constexpr int PL = C / 64;
    const float* asp = a_s + hd * C + lane * PL;
    const float* adp = a_d + hd * C + lane * PL;
    for (int n = wv; n < 36; n += 4) {
        const u16* hp = h + (size_t)(nb + n) * (H * C) + hd * C + lane * PL;
        u16 hb[PL];
        if constexpr (PL == 4) { *(uint2*)hb = *(const uint2*)hp; }
        else                   { *(uint4*)hb = *(const uint4*)hp; }
        float s1 = 0.f, s2 = 0.f;
        #pragma unroll
        for (int i = 0; i < PL; i++) {
            const float hv = b2f(hb[i]);
            s1 += hv * asp[i];
            s2 += hv * adp[i];
        }
        #pragma unroll
        for (int off = 32; off > 0; off >>= 1) {
            s1 += __shfl_down(s1, off);
            s2 += __shfl_down(s2, off);
        }
        if (lane == 0) { asl[n] = s1; adl[n] = s2; }
    }
    __syncthreads();
    if (t >= 36) return;
    const float ad = adl[t];
    float row[36];
    float mx = -1e30f;
    #pragma unroll
    for (int s = 0; s < 36; s++) {
        float v = asl[s] + ad; v = (v > 0.f) ? v : 0.2f * v;
        row[s] = v; mx = fmaxf(mx, v);
    }
    float sum = 0.f;
    #pragma unroll
    for (int s = 0; s < 36; s++) { row[s] = expf(row[s] - mx); sum += row[s]; }
    const float inv = (MEAN ? 0.2f : 1.0f) / (sum + 1e-16f);
    float* o = alphaG + (((size_t)b * H + hd) * 36 + t) * 36;
    #pragma unroll
    for (int s = 0; s < 36; s++) o[s] = row[s] * inv;
}

// ---------------------------------------------------------------------------
// Aggregation, mean layer (3): grid (512/64, B_IMG), 192 threads.
// ---------------------------------------------------------------------------
__global__ __launch_bounds__(192)
void attn_agg_mean(const u16* __restrict__ h, const float* __restrict__ alphaG,
                   const float* __restrict__ b3, float* __restrict__ outp)
{
    __shared__ __align__(16) u16 hl[36 * 64];
    __shared__ float al[36 * 36];
    const int b = blockIdx.y, sl = blockIdx.x;
    const int nb = b * NOBJ, cb = sl * 64;
    const int t = threadIdx.x;

    float ac[2][8] = {};   // constant-indexed only (p unrolled, j literal)
    for (int hd = 0; hd < 5; hd++) {
        if (hd) __syncthreads();   // protect hl/al overwrite
        for (int e = t; e < 36 * 8; e += 192) {
            const int row = e >> 3, col = (e & 7) * 8;
            *(uint4*)&hl[row * 64 + col] =
                *(const uint4*)&h[(size_t)(nb + row) * 2560 + hd * 512 + cb + col];
        }
        const float* ap = alphaG + ((size_t)b * 5 + hd) * 1296;
        for (int e = t; e < 1296; e += 192) al[e] = ap[e];
        __syncthreads();
        #pragma unroll
        for (int p = 0; p < 2; p++) {
            const int e = p * 192 + t;
            if (e < 288) {
                const int d = e >> 3, c8 = (e & 7) * 8;
                for (int s = 0; s < 36; s++) {
                    const float av = al[d * 36 + s];
                    const uint4 hv = *(const uint4*)&hl[s * 64 + c8];
                    ac[p][0] += av * b2f((u16)hv.x);  ac[p][1] += av * b2f((u16)(hv.x >> 16));
                    ac[p][2] += av * b2f((u16)hv.y);  ac[p][3] += av * b2f((u16)(hv.y >> 16));
                    ac[p][4] += av * b2f((u16)hv.z);  ac[p][5] += av * b2f((u16)(hv.z >> 16));
                    ac[p][6] += av * b2f((u16)hv.w);  ac[p][7] += av * b2f((u16)(hv.w >> 16));
                }
            }
        }
    }
    #pragma unroll
    for (int p = 0; p < 2; p++) {
        const int e = p * 192 + t;
        if (e < 288) {
            const int d = e >> 3, c8 = (e & 7) * 8;
            float* op = &outp[(size_t)(nb + d) * 512 + cb + c8];
            const float* bp = &b3[cb + c8];
            float4 o0, o1;
            o0.x = ac[p][0] + bp[0]; o0.y = ac[p][1] + bp[1];
            o0.z = ac[p][2] + bp[2]; o0.w = ac[p][3] + bp[3];
            o1.x = ac[p][4] + bp[4]; o1.y = ac[p][5] + bp[5];
            o1.z = ac[p][6] + bp[6]; o1.w = ac[p][7] + bp[7];
            *(float4*)op = o0;
            *(float4*)(op + 4) = o1;
        }
    }
}

// ---------------------------------------------------------------------------
// Workspace ~73.5 MB, lifetime-packed:
//  E: qe_c 0.66M | of_c 18.87M
//  A (23.59M): WqT(10.49)+qpart(10.49 @ +10.49, splitK=10) -> x -> g1 -> h3
//  B ( 9.44M): WvT(8.39), q(1.05 @ +8.39) -> g2
//  C ( 9.44M): h1 -> h2
//  F ( 5.24M): W3T (S0 -> S11 read)  then  alphaG (S13 -> S14)   [union]
//  G ( 6.29M): W1T(4.19) + W2T(2.10)  (S0 -> S8 read)
// ---------------------------------------------------------------------------
extern "C" void kernel_launch(void* const* d_in, const int* in_sizes, int n_in,
                              void* d_out, int out_size, void* d_ws, size_t ws_size,
                              hipStream_t stream)
{
    const float* qe  = (const float*)d_in[0];    // [128,2400]
    const float* of  = (const float*)d_in[1];    // [4608,2048]
    const float* Wq  = (const float*)d_in[3];    // [2400,2048]
    const float* bq  = (const float*)d_in[4];
    const float* Wv  = (const float*)d_in[5];    // [2048,2048]
    const float* bv  = (const float*)d_in[6];
    const float* W1  = (const float*)d_in[7];    // [2048,1024]
    const float* a1s = (const float*)d_in[8];
    const float* a1d = (const float*)d_in[9];
    const float* b1  = (const float*)d_in[10];
    const float* W2  = (const float*)d_in[11];   // [1024,1024]
    const float* a2s = (const float*)d_in[12];
    const float* a2d = (const float*)d_in[13];
    const float* b2  = (const float*)d_in[14];
    const float* W3  = (const float*)d_in[15];   // [1024,2560]
    const float* a3s = (const float*)d_in[16];
    const float* a3d = (const float*)d_in[17];
    const float* b3  = (const float*)d_in[18];
    float* out = (float*)d_out;
    (void)ws_size; (void)in_sizes; (void)n_in; (void)out_size;

    char* W0 = (char*)d_ws;
    size_t off = 0;
    auto alloc = [&](size_t bytes) -> char* {
        char* p = W0 + off; off += (bytes + 255) & ~(size_t)255; return p;
    };
    u16* qe_c = (u16*)alloc(128ull * 2560 * 2);
    u16* of_c = (u16*)alloc(4608ull * 2048 * 2);
    const size_t szA = 4608ull * 2560 * 2;
    const size_t szB = 4608ull * 1024 * 2;
    const size_t szC = 4608ull * 1024 * 2;
    char* Abase = alloc(szA);
    char* Bbase = alloc(szB);
    char* Cbase = alloc(szC);
    char* Fbase = alloc(2560ull * 1024 * 2);   // 5.24 MB union: W3T then alphaG
    char* Gbase = alloc(1024ull * 2048 * 2 + 1024ull * 1024 * 2);  // W1T + W2T

    u16*   WqT   = (u16*)Abase;                           // [2048,2560]
    float* qpart = (float*)(Abase + 2048ull * 2560 * 2);  // 10 x 1.05 MB (splitK=10)
    u16*   x     = (u16*)Abase;
    u16*   g1    = (u16*)Abase;
    u16*   h3    = (u16*)Abase;
    u16*   WvT   = (u16*)Bbase;                           // [2048,2048]
    float* q     = (float*)(Bbase + 2048ull * 2048 * 2);
    u16*   g2    = (u16*)Bbase;
    u16*   h1    = (u16*)Cbase;
    u16*   h2    = (u16*)Cbase;
    u16*   W3T   = (u16*)Fbase;                           // [2560,1024], S0->S11
    float* alphaG = (float*)Fbase;                        // 3.32 MB, S13->S14
    u16*   W1T   = (u16*)Gbase;                           // [1024,2048]
    u16*   W2T   = (u16*)(Gbase + 1024ull * 2048 * 2);    // [1024,1024]

    // S0: ALL converts + ALL weight transposes in ONE launch
    prep_all<<<dim3(14208), 256, 0, stream>>>(of, of_c, qe, qe_c,
                                              Wq, WqT, Wv, WvT, W3, W3T,
                                              W1, W1T, W2, W2T);

    // S2-S3: q = qe @ Wq + bq   (BM=64, splitK=10 -> 320 blocks)
    gemm_tn<1, 64><<<dim3(16, 2, 10), 256, 0, stream>>>(qe_c, WqT, 128, 2048, 2560, 256,
                                                        qpart, nullptr, nullptr, nullptr);
    qcombine<<<dim3(128 * 2048 / 256), 256, 0, stream>>>(qpart, bq, q, 128 * 2048, 10);

    // S4: x = (of @ Wv + bv) * q_rep   (BM=128, 576 blocks — frozen best)
    gemm_tn<2, 128><<<dim3(16, 36, 1), 256, 0, stream>>>(of_c, WvT, 4608, 2048, 2048, 2048,
                                                         nullptr, x, bv, q);

    // S6-S7: layer 1   (BM=64 -> 576 blocks, 6 blocks/CU)
    gemm_tn<0, 64><<<dim3(8, 72, 1), 256, 0, stream>>>(x, W1T, 4608, 1024, 2048, 2048,
                                                       nullptr, h1, nullptr, nullptr);
    attn_kernel<4, 256, 1><<<dim3(4, B_IMG), 256, 0, stream>>>(h1, a1s, a1d, b1, nullptr, g1);

    // S8-S9: layer 2 (+ residual g1)   (BM=64 -> 576 blocks)
    gemm_tn<0, 64><<<dim3(8, 72, 1), 256, 0, stream>>>(g1, W2T, 4608, 1024, 1024, 1024,
                                                       nullptr, h2, nullptr, nullptr);
    attn_kernel<4, 256, 2><<<dim3(4, B_IMG), 256, 0, stream>>>(h2, a2s, a2d, b2, g1, g2);

    // S11-S14: layer 3 (5 heads, mean + b3) -> fp32 out   (BM=128, 720 blocks)
    gemm_tn<0, 128><<<dim3(20, 36, 1), 256, 0, stream>>>(g2, W3T, 4608, 2560, 1024, 1024,
                                                         nullptr, h3, nullptr, nullptr);
    al_alpha<5, 512, true><<<dim3(5, B_IMG), 256, 0, stream>>>(h3, a3s, a3d, alphaG);
    attn_agg_mean<<<dim3(8, B_IMG), 192, 0, stream>>>(h3, alphaG, b3, out);
}

// Round 13
// 457.301 us; speedup vs baseline: 1.0544x; 1.0544x over previous
//
#include <hip/hip_runtime.h>
#include <hip/hip_bf16.h>

typedef unsigned short u16;
typedef __bf16 bf16x8 __attribute__((ext_vector_type(8)));
typedef float f32x4 __attribute__((ext_vector_type(4)));

#define B_IMG 128
#define NOBJ  36
#define NNODE (B_IMG * NOBJ)

__device__ __forceinline__ float b2f(u16 u) {
    union { unsigned int i; float f; } v; v.i = ((unsigned int)u) << 16; return v.f;
}
__device__ __forceinline__ u16 f2b(float f) {
    union { float f; unsigned int i; } v; v.f = f;
    unsigned int u = v.i;
    return (u16)((u + 0x7fffu + ((u >> 16) & 1u)) >> 16);   // RNE
}

// ---------------------------------------------------------------------------
// 64x64 convert+transpose tile body: src [Rs, C] fp32 -> dst [C, Rd] bf16,
// rows k >= Rs zero-filled.  Reads 256 B/instr, writes 128 B/instr.
// ---------------------------------------------------------------------------
__device__ __forceinline__ void tr64_body(u16 (*tile)[65], const float* __restrict__ src,
                                          u16* __restrict__ dst, int Rs, int Rd, int C,
                                          int tb, int t)
{
    const int ntx = C >> 6;
    const int ty = tb / ntx, tx = tb - ty * ntx;
    const int bx = tx * 64, by = ty * 64;     // bx: src col / dst row; by: src row (k)
    const int x = t & 63, y = t >> 6;         // 64 x 4
    #pragma unroll
    for (int i = y; i < 64; i += 4) {
        const int k = by + i;
        tile[i][x] = (k < Rs) ? f2b(src[(size_t)k * C + bx + x]) : (u16)0;
    }
    __syncthreads();
    #pragma unroll
    for (int i = y; i < 64; i += 4)
        dst[(size_t)(bx + i) * Rd + by + x] = tile[x][i];
}

// ---------------------------------------------------------------------------
// Fused S0 prep (one launch): of pack | qe pad | WqT | WvT | W3T | W1T | W2T.
// Block ranges: [0,9216) of | [+1280) qe | [+1280) Wq | [+1024) Wv |
// [+640) W3 | [+512) W1 | [+256) W2.   Total 14208.
// ---------------------------------------------------------------------------
__global__ __launch_bounds__(256)
void prep_all(const float* __restrict__ of, u16* __restrict__ of_c,
              const float* __restrict__ qe, u16* __restrict__ qe_c,
              const float* __restrict__ Wq, u16* __restrict__ WqT,
              const float* __restrict__ Wv, u16* __restrict__ WvT,
              const float* __restrict__ W3, u16* __restrict__ W3T,
              const float* __restrict__ W1, u16* __restrict__ W1T,
              const float* __restrict__ W2, u16* __restrict__ W2T)
{
    __shared__ u16 tile[64][65];
    int b = blockIdx.x;
    const int t = threadIdx.x;
    if (b < 9216) {
        const int i = b * 256 + t;               // < 4608*2048/4 exactly
        const float4 f = ((const float4*)of)[i];
        ushort4 o; o.x = f2b(f.x); o.y = f2b(f.y); o.z = f2b(f.z); o.w = f2b(f.w);
        ((ushort4*)of_c)[i] = o;
        return;
    }
    b -= 9216;
    if (b < 1280) {
        const int i = b * 256 + t;               // < 128*2560 exactly
        const int r = i / 2560, c = i - r * 2560;
        qe_c[i] = (c < 2400) ? f2b(qe[r * 2400 + c]) : (u16)0;
        return;
    }
    b -= 1280;
    if (b < 1280) { tr64_body(tile, Wq, WqT, 2400, 2560, 2048, b, t); return; }
    b -= 1280;
    if (b < 1024) { tr64_body(tile, Wv, WvT, 2048, 2048, 2048, b, t); return; }
    b -= 1024;
    if (b < 640)  { tr64_body(tile, W3, W3T, 1024, 1024, 2560, b, t); return; }
    b -= 640;
    if (b < 512)  { tr64_body(tile, W1, W1T, 2048, 2048, 1024, b, t); return; }
    b -= 512;
    tr64_body(tile, W2, W2T, 1024, 1024, 1024, b, t);
}

// ---------------------------------------------------------------------------
// TN MFMA GEMM: C[M,N] = A[M,K] * Bt[N,K]^T   (bf16 in, fp32 acc)
// MEASURED-BEST r7/r10 structure, fully reverted (r12's BM=64 variant is
// implicated in the 482us regression): 128x128 tile, BK=32, 4 waves 2x2,
// 4x4 16x16x32 MFMA/iter, A+B via global_load_lds, 2 stages = 32 KB,
// vmcnt(0)+barrier/iter, bijective XCD block swizzle.  FROZEN.
// EPI: 1 = splitK fp32 partial, 2 = +bias then *qmul -> bf16, 0 = bf16.
// ---------------------------------------------------------------------------
template<int EPI>
__global__ __launch_bounds__(256, 4)
void gemm_tn(const u16* __restrict__ A, const u16* __restrict__ Bt,
             int M, int N, int K, int kLen,
             float* __restrict__ Cf, u16* __restrict__ Cb,
             const float* __restrict__ bias, const float* __restrict__ qmul)
{
    __shared__ __align__(16) u16 lds[2 * 8192];   // 32 KB

    const int t    = threadIdx.x;
    const int lane = t & 63;
    const int wave = t >> 6;
    const int wr = wave >> 1, wc = wave & 1;
    const int quad = lane >> 4, l16 = lane & 15;

    // XCD swizzle: contiguous chunk of the xy-grid per XCD (bijective: nxy%8==0)
    const int nxy = gridDim.x * gridDim.y;
    int bid = blockIdx.x + gridDim.x * blockIdx.y;
    const int cpx = nxy >> 3;
    bid = (bid & 7) * cpx + (bid >> 3);
    const int bx = bid % gridDim.x, by = bid / gridDim.x;

    const int rowBase = by * 128;
    const int colBase = bx * 128;
    const int k0 = blockIdx.z * kLen;

    // staging: wave w owns rows [w*32, w*32+32); 2 DMA chunks of 16 rows per matrix.
    const u16* gA0 = A  + (size_t)(rowBase + wave * 32 + (lane >> 2)) * K + k0 + (lane & 3) * 8;
    const u16* gA1 = gA0 + 16 * (size_t)K;
    const u16* gB0 = Bt + (size_t)(colBase + wave * 32 + (lane >> 2)) * K + k0 + (lane & 3) * 8;
    const u16* gB1 = gB0 + 16 * (size_t)K;
    const int ro = wave * 1024;   // 32 rows * 32 u16

    int afr[4], bfr[4];
    #pragma unroll
    for (int r = 0; r < 4; r++) afr[r] = (wr * 64 + r * 16 + l16) * 32 + quad * 8;
    #pragma unroll
    for (int c = 0; c < 4; c++) bfr[c] = 4096 + (wc * 64 + c * 16 + l16) * 32 + quad * 8;

    f32x4 acc[4][4];
    #pragma unroll
    for (int r = 0; r < 4; r++)
        #pragma unroll
        for (int c = 0; c < 4; c++)
            acc[r][c] = (f32x4){0.f, 0.f, 0.f, 0.f};

    auto gld = [](const u16* g, u16* s) {
        __builtin_amdgcn_global_load_lds(
            (const __attribute__((address_space(1))) void*)g,
            (__attribute__((address_space(3))) void*)s, 16, 0, 0);
    };
    auto dma_stage = [&](int it, int st) {
        const int kk = it * 32;
        const int bo = st * 8192;
        gld(gA0 + kk, &lds[bo + ro]);
        gld(gA1 + kk, &lds[bo + ro + 512]);
        gld(gB0 + kk, &lds[bo + 4096 + ro]);
        gld(gB1 + kk, &lds[bo + 4096 + ro + 512]);
    };

    const int nIter = kLen >> 5;   // kLen % 32 == 0 at all call sites
    dma_stage(0, 0);

    for (int it = 0; it < nIter; ++it) {
        asm volatile("s_waitcnt vmcnt(0)\n\ts_barrier" ::: "memory");
        if (it + 1 < nIter) dma_stage(it + 1, (it + 1) & 1);
        const int bo = (it & 1) * 8192;
        bf16x8 avf[4], bvf[4];
        #pragma unroll
        for (int r = 0; r < 4; r++) avf[r] = *(const bf16x8*)&lds[bo + afr[r]];
        #pragma unroll
        for (int c = 0; c < 4; c++) bvf[c] = *(const bf16x8*)&lds[bo + bfr[c]];
        #pragma unroll
        for (int r = 0; r < 4; r++)
            #pragma unroll
            for (int c = 0; c < 4; c++)
                acc[r][c] = __builtin_amdgcn_mfma_f32_16x16x32_bf16(avf[r], bvf[c], acc[r][c], 0, 0, 0);
    }

    // epilogue: D row = quad*4+reg, col = l16
    #pragma unroll
    for (int r = 0; r < 4; r++) {
        const int mBase = rowBase + wr * 64 + r * 16 + quad * 4;
        #pragma unroll
        for (int c = 0; c < 4; c++) {
            const int n = colBase + wc * 64 + c * 16 + l16;
            #pragma unroll
            for (int e = 0; e < 4; e++) {
                const int m = mBase + e;
                float v = acc[r][c][e];
                if (EPI == 1) {
                    Cf[((size_t)blockIdx.z * M + m) * N + n] = v;
                } else if (EPI == 2) {
                    v += bias[n];
                    v *= qmul[(size_t)(m / NOBJ) * N + n];
                    Cb[(size_t)m * N + n] = f2b(v);
                } else {
                    Cb[(size_t)m * N + n] = f2b(v);
                }
            }
        }
    }
}

// ---------------------------------------------------------------------------
__global__ __launch_bounds__(256)
void qcombine(const float* __restrict__ p, const float* __restrict__ bias,
              float* __restrict__ q, int MN, int S)
{
    const int i = blockIdx.x * 256 + threadIdx.x;
    float s = 0.f;
    for (int z = 0; z < S; z++) s += p[(size_t)z * MN + i];
    q[i] = s + bias[i & 2047];
}

// ---------------------------------------------------------------------------
// Fused attention per (image, head) — layers 1/2 (r10: uint4 hl reads).
// MODE 1: relu(agg+b) -> g (bf16);  MODE 2: relu(agg+b)+resid -> g
// ---------------------------------------------------------------------------
template<int H, int C, int MODE>
__global__ __launch_bounds__(256)
void attn_kernel(const u16* __restrict__ h, const float* __restrict__ a_src,
                 const float* __restrict__ a_dst, const float* __restrict__ bias,
                 const u16* __restrict__ resid, u16* __restrict__ outb)
{
    __shared__ __align__(16) u16 hl[36 * C];
    __shared__ float alpha[36 * 36];
    __shared__ float asl[36], adl[36];
    __shared__ float psum[36][8][2];
    const int b = blockIdx.y, hd = blockIdx.x;
    const int t = threadIdx.x;
    const int nb = b * NOBJ;
    constexpr int CH = C / 8;
    for (int e = t; e < 36 * CH; e += 256) {
        const int row = e / CH, col = (e - row * CH) * 8;
        *(uint4*)&hl[row * C + col] = *(const uint4*)&h[(size_t)(nb + row) * (H * C) + hd * C + col];
    }
    __syncthreads();
    constexpr int SEG = C / 8;
    for (int e = t; e < 36 * 8; e += 256) {
        const int n = e >> 3, sg = e & 7;
        const u16*   hp = &hl[n * C + sg * SEG];
        const float* as = a_src + hd * C + sg * SEG;
        const float* ad = a_dst + hd * C + sg * SEG;
        float s1 = 0.f, s2 = 0.f;
        #pragma unroll 8
        for (int i = 0; i < SEG; i++) {
            const float hv = b2f(hp[i]);
            s1 += hv * as[i]; s2 += hv * ad[i];
        }
        psum[n][sg][0] = s1; psum[n][sg][1] = s2;
    }
    __syncthreads();
    if (t < 36) {
        float s1 = 0.f, s2 = 0.f;
        #pragma unroll
        for (int sg = 0; sg < 8; sg++) { s1 += psum[t][sg][0]; s2 += psum[t][sg][1]; }
        asl[t] = s1; adl[t] = s2;
    }
    __syncthreads();
    if (t < 36) {
        const float ad = adl[t];
        float mx = -1e30f;
        for (int s = 0; s < 36; s++) {
            float v = asl[s] + ad; v = (v > 0.f) ? v : 0.2f * v;
            alpha[t * 36 + s] = v; mx = fmaxf(mx, v);
        }
        float sum = 0.f;
        for (int s = 0; s < 36; s++) { const float ex = expf(alpha[t * 36 + s] - mx); alpha[t * 36 + s] = ex; sum += ex; }
        const float inv = 1.f / (sum + 1e-16f);
        for (int s = 0; s < 36; s++) alpha[t * 36 + s] *= inv;
    }
    __syncthreads();
    constexpr int NC8 = C / 8;
    for (int e = t; e < 36 * NC8; e += 256) {
        const int d = e / NC8, c8 = (e - d * NC8) * 8;
        float a0 = 0, a1 = 0, a2 = 0, a3 = 0, a4 = 0, a5 = 0, a6 = 0, a7 = 0;
        for (int s = 0; s < 36; s++) {
            const float al = alpha[d * 36 + s];
            const uint4 hv = *(const uint4*)&hl[s * C + c8];
            a0 += al * b2f((u16)hv.x);  a1 += al * b2f((u16)(hv.x >> 16));
            a2 += al * b2f((u16)hv.y);  a3 += al * b2f((u16)(hv.y >> 16));
            a4 += al * b2f((u16)hv.z);  a5 += al * b2f((u16)(hv.z >> 16));
            a6 += al * b2f((u16)hv.w);  a7 += al * b2f((u16)(hv.w >> 16));
        }
        const int n = nb + d;
        const size_t base = (size_t)n * (H * C) + hd * C + c8;
        const int bb = hd * C + c8;
        float v0 = a0 + bias[bb + 0], v1 = a1 + bias[bb + 1];
        float v2 = a2 + bias[bb + 2], v3 = a3 + bias[bb + 3];
        float v4 = a4 + bias[bb + 4], v5 = a5 + bias[bb + 5];
        float v6 = a6 + bias[bb + 6], v7 = a7 + bias[bb + 7];
        v0 = v0 > 0.f ? v0 : 0.f; v1 = v1 > 0.f ? v1 : 0.f;
        v2 = v2 > 0.f ? v2 : 0.f; v3 = v3 > 0.f ? v3 : 0.f;
        v4 = v4 > 0.f ? v4 : 0.f; v5 = v5 > 0.f ? v5 : 0.f;
        v6 = v6 > 0.f ? v6 : 0.f; v7 = v7 > 0.f ? v7 : 0.f;
        if (MODE == 2) {
            const uint4 rv = *(const uint4*)&resid[base];
            v0 += b2f((u16)rv.x); v1 += b2f((u16)(rv.x >> 16));
            v2 += b2f((u16)rv.y); v3 += b2f((u16)(rv.y >> 16));
            v4 += b2f((u16)rv.z); v5 += b2f((u16)(rv.z >> 16));
            v6 += b2f((u16)rv.w); v7 += b2f((u16)(rv.w >> 16));
        }
        uint4 ov;
        ov.x = (unsigned)f2b(v0) | ((unsigned)f2b(v1) << 16);
        ov.y = (unsigned)f2b(v2) | ((unsigned)f2b(v3) << 16);
        ov.z = (unsigned)f2b(v4) | ((unsigned)f2b(v5) << 16);
        ov.w = (unsigned)f2b(v6) | ((unsigned)f2b(v7) << 16);
        *(uint4*)&outb[base] = ov;
    }
}

// ---------------------------------------------------------------------------
// Fused al + softmax per (head, image), layer 3 -> alphaG (0.2 mean folded).
// ---------------------------------------------------------------------------
template<int H, int C, bool MEAN>
__global__ __launch_bounds__(256)
void al_alpha(const u16* __restrict__ h, const float* __restrict__ a_s,
              const float* __restrict__ a_d, float* __restrict__ alphaG)
{
    __shared__ float asl[36], adl[36];
    const int hd = blockIdx.x, b = blockIdx.y;
    const int nb = b * NOBJ;
    const int t = threadIdx.x, wv = t >> 6, lane = t & 63;
    constexpr int PL = C / 64;
    const float* asp = a_s + hd * C + lane * PL;
    const float* adp = a_d + hd * C + lane * PL;
    for (int n = wv; n < 36; n += 4) {
        const u16* hp = h + (size_t)(nb + n) * (H * C) + hd * C + lane * PL;
        u16 hb[PL];
        if constexpr (PL == 4) { *(uint2*)hb = *(const uint2*)hp; }
        else                   { *(uint4*)hb = *(const uint4*)hp; }
        float s1 = 0.f, s2 = 0.f;
        #pragma unroll
        for (int i = 0; i < PL; i++) {
            const float hv = b2f(hb[i]);
            s1 += hv * asp[i];
            s2 += hv * adp[i];
        }
        #pragma unroll
        for (int off = 32; off > 0; off >>= 1) {
            s1 += __shfl_down(s1, off);
            s2 += __shfl_down(s2, off);
        }
        if (lane == 0) { asl[n] = s1; adl[n] = s2; }
    }
    __syncthreads();
    if (t >= 36) return;
    const float ad = adl[t];
    float row[36];
    float mx = -1e30f;
    #pragma unroll
    for (int s = 0; s < 36; s++) {
        float v = asl[s] + ad; v = (v > 0.f) ? v : 0.2f * v;
        row[s] = v; mx = fmaxf(mx, v);
    }
    float sum = 0.f;
    #pragma unroll
    for (int s = 0; s < 36; s++) { row[s] = expf(row[s] - mx); sum += row[s]; }
    const float inv = (MEAN ? 0.2f : 1.0f) / (sum + 1e-16f);
    float* o = alphaG + (((size_t)b * H + hd) * 36 + t) * 36;
    #pragma unroll
    for (int s = 0; s < 36; s++) o[s] = row[s] * inv;
}

// ---------------------------------------------------------------------------
// Aggregation, mean layer (3), v2: grid (16 slabs of 32 cols, B_IMG),
// 192 threads, ONE item (d, c8) per thread (t<144).  2048 blocks -> 8
// blocks/CU, 24 waves/CU (was 4 blocks/12 waves at 95us, latency-bound:
// MfmaUtil 0 / VALU 20% / hbm 4.5%).  Even/odd-s dual accumulators halve
// the dependent-FMA chain.  hl reads: 16-lane broadcast + 64B contiguous
// per wave = conflict-free; al reads 2-way (free).
// ---------------------------------------------------------------------------
__global__ __launch_bounds__(192)
void attn_agg_mean(const u16* __restrict__ h, const float* __restrict__ alphaG,
                   const float* __restrict__ bias3, float* __restrict__ outp)
{
    __shared__ __align__(16) u16 hl[36 * 32];
    __shared__ float al[36 * 36];
    const int b = blockIdx.y, sl = blockIdx.x;    // sl in [0,16)
    const int nb = b * NOBJ, cb = sl * 32;
    const int t = threadIdx.x;
    const int d = t >> 2, c8 = (t & 3) * 8;       // valid when t < 144

    float e0 = 0, e1 = 0, e2 = 0, e3 = 0, e4 = 0, e5 = 0, e6 = 0, e7 = 0;
    float o0 = 0, o1 = 0, o2 = 0, o3 = 0, o4 = 0, o5 = 0, o6 = 0, o7 = 0;

    for (int hd = 0; hd < 5; hd++) {
        if (hd) __syncthreads();   // protect hl/al overwrite
        if (t < 144) {
            // t -> (row = t>>2, col = (t&3)*8): 144 uint4 = 36 rows x 32 u16
            *(uint4*)&hl[(t >> 2) * 32 + (t & 3) * 8] =
                *(const uint4*)&h[(size_t)(nb + (t >> 2)) * 2560 + hd * 512 + cb + (t & 3) * 8];
        }
        const float* ap = alphaG + ((size_t)b * 5 + hd) * 1296;
        for (int e = t; e < 1296; e += 192) al[e] = ap[e];
        __syncthreads();
        if (t < 144) {
            const float* arow = &al[d * 36];
            #pragma unroll
            for (int s = 0; s < 36; s += 2) {
                {
                    const float av = arow[s];
                    const uint4 hv = *(const uint4*)&hl[s * 32 + c8];
                    e0 += av * b2f((u16)hv.x);  e1 += av * b2f((u16)(hv.x >> 16));
                    e2 += av * b2f((u16)hv.y);  e3 += av * b2f((u16)(hv.y >> 16));
                    e4 += av * b2f((u16)hv.z);  e5 += av * b2f((u16)(hv.z >> 16));
                    e6 += av * b2f((u16)hv.w);  e7 += av * b2f((u16)(hv.w >> 16));
                }
                {
                    const float av = arow[s + 1];
                    const uint4 hv = *(const uint4*)&hl[(s + 1) * 32 + c8];
                    o0 += av * b2f((u16)hv.x);  o1 += av * b2f((u16)(hv.x >> 16));
                    o2 += av * b2f((u16)hv.y);  o3 += av * b2f((u16)(hv.y >> 16));
                    o4 += av * b2f((u16)hv.z);  o5 += av * b2f((u16)(hv.z >> 16));
                    o6 += av * b2f((u16)hv.w);  o7 += av * b2f((u16)(hv.w >> 16));
                }
            }
        }
    }
    if (t < 144) {
        float* op = &outp[(size_t)(nb + d) * 512 + cb + c8];
        const float* bp = &bias3[cb + c8];
        float4 w0, w1;
        w0.x = e0 + o0 + bp[0]; w0.y = e1 + o1 + bp[1];
        w0.z = e2 + o2 + bp[2]; w0.w = e3 + o3 + bp[3];
        w1.x = e4 + o4 + bp[4]; w1.y = e5 + o5 + bp[5];
        w1.z = e6 + o6 + bp[6]; w1.w = e7 + o7 + bp[7];
        *(float4*)op = w0;
        *(float4*)(op + 4) = w1;
    }
}

// ---------------------------------------------------------------------------
// Workspace ~73.5 MB, lifetime-packed:
//  E: qe_c 0.66M | of_c 18.87M
//  A (23.59M): WqT(10.49)+qpart(10.49 @ +10.49, splitK=10) -> x -> g1 -> h3
//  B ( 9.44M): WvT(8.39), q(1.05 @ +8.39) -> g2
//  C ( 9.44M): h1 -> h2
//  F ( 5.24M): W3T (S0 -> S11 read)  then  alphaG (S13 -> S14)   [union]
//  G ( 6.29M): W1T(4.19) + W2T(2.10)  (S0 -> S8 read)
// ---------------------------------------------------------------------------
extern "C" void kernel_launch(void* const* d_in, const int* in_sizes, int n_in,
                              void* d_out, int out_size, void* d_ws, size_t ws_size,
                              hipStream_t stream)
{
    const float* qe  = (const float*)d_in[0];    // [128,2400]
    const float* of  = (const float*)d_in[1];    // [4608,2048]
    const float* Wq  = (const float*)d_in[3];    // [2400,2048]
    const float* bq  = (const float*)d_in[4];
    const float* Wv  = (const float*)d_in[5];    // [2048,2048]
    const float* bv  = (const float*)d_in[6];
    const float* W1  = (const float*)d_in[7];    // [2048,1024]
    const float* a1s = (const float*)d_in[8];
    const float* a1d = (const float*)d_in[9];
    const float* b1  = (const float*)d_in[10];
    const float* W2  = (const float*)d_in[11];   // [1024,1024]
    const float* a2s = (const float*)d_in[12];
    const float* a2d = (const float*)d_in[13];
    const float* b2  = (const float*)d_in[14];
    const float* W3  = (const float*)d_in[15];   // [1024,2560]
    const float* a3s = (const float*)d_in[16];
    const float* a3d = (const float*)d_in[17];
    const float* b3  = (const float*)d_in[18];
    float* out = (float*)d_out;
    (void)ws_size; (void)in_sizes; (void)n_in; (void)out_size;

    char* W0 = (char*)d_ws;
    size_t off = 0;
    auto alloc = [&](size_t bytes) -> char* {
        char* p = W0 + off; off += (bytes + 255) & ~(size_t)255; return p;
    };
    u16* qe_c = (u16*)alloc(128ull * 2560 * 2);
    u16* of_c = (u16*)alloc(4608ull * 2048 * 2);
    const size_t szA = 4608ull * 2560 * 2;
    const size_t szB = 4608ull * 1024 * 2;
    const size_t szC = 4608ull * 1024 * 2;
    char* Abase = alloc(szA);
    char* Bbase = alloc(szB);
    char* Cbase = alloc(szC);
    char* Fbase = alloc(2560ull * 1024 * 2);   // 5.24 MB union: W3T then alphaG
    char* Gbase = alloc(1024ull * 2048 * 2 + 1024ull * 1024 * 2);  // W1T + W2T

    u16*   WqT   = (u16*)Abase;                           // [2048,2560]
    float* qpart = (float*)(Abase + 2048ull * 2560 * 2);  // 10 x 1.05 MB (splitK=10)
    u16*   x     = (u16*)Abase;
    u16*   g1    = (u16*)Abase;
    u16*   h3    = (u16*)Abase;
    u16*   WvT   = (u16*)Bbase;                           // [2048,2048]
    float* q     = (float*)(Bbase + 2048ull * 2048 * 2);
    u16*   g2    = (u16*)Bbase;
    u16*   h1    = (u16*)Cbase;
    u16*   h2    = (u16*)Cbase;
    u16*   W3T   = (u16*)Fbase;                           // [2560,1024], S0->S11
    float* alphaG = (float*)Fbase;                        // 3.32 MB, S13->S14
    u16*   W1T   = (u16*)Gbase;                           // [1024,2048]
    u16*   W2T   = (u16*)(Gbase + 1024ull * 2048 * 2);    // [1024,1024]

    // S0: ALL converts + ALL weight transposes in ONE launch
    prep_all<<<dim3(14208), 256, 0, stream>>>(of, of_c, qe, qe_c,
                                              Wq, WqT, Wv, WvT, W3, W3T,
                                              W1, W1T, W2, W2T);

    // S2-S3: q = qe @ Wq + bq   (splitK=10 x 256: 160 blocks)
    gemm_tn<1><<<dim3(16, 1, 10), 256, 0, stream>>>(qe_c, WqT, 128, 2048, 2560, 256,
                                                    qpart, nullptr, nullptr, nullptr);
    qcombine<<<dim3(128 * 2048 / 256), 256, 0, stream>>>(qpart, bq, q, 128 * 2048, 10);

    // S4: x = (of @ Wv + bv) * q_rep   (576 blocks — frozen best)
    gemm_tn<2><<<dim3(16, 36, 1), 256, 0, stream>>>(of_c, WvT, 4608, 2048, 2048, 2048,
                                                    nullptr, x, bv, q);

    // S6-S7: layer 1 (fused attention)
    gemm_tn<0><<<dim3(8, 36, 1), 256, 0, stream>>>(x, W1T, 4608, 1024, 2048, 2048,
                                                   nullptr, h1, nullptr, nullptr);
    attn_kernel<4, 256, 1><<<dim3(4, B_IMG), 256, 0, stream>>>(h1, a1s, a1d, b1, nullptr, g1);

    // S8-S9: layer 2 (+ residual g1, fused attention)
    gemm_tn<0><<<dim3(8, 36, 1), 256, 0, stream>>>(g1, W2T, 4608, 1024, 1024, 1024,
                                                   nullptr, h2, nullptr, nullptr);
    attn_kernel<4, 256, 2><<<dim3(4, B_IMG), 256, 0, stream>>>(h2, a2s, a2d, b2, g1, g2);

    // S11-S14: layer 3 (5 heads, mean + b3) -> fp32 out
    gemm_tn<0><<<dim3(20, 36, 1), 256, 0, stream>>>(g2, W3T, 4608, 2560, 1024, 1024,
                                                    nullptr, h3, nullptr, nullptr);
    al_alpha<5, 512, true><<<dim3(5, B_IMG), 256, 0, stream>>>(h3, a3s, a3d, alphaG);
    attn_agg_mean<<<dim3(16, B_IMG), 192, 0, stream>>>(h3, alphaG, b3, out);
}

// Round 14
// 413.713 us; speedup vs baseline: 1.1655x; 1.1054x over previous
//
#include <hip/hip_runtime.h>
#include <hip/hip_bf16.h>

typedef unsigned short u16;
typedef __bf16 bf16x8 __attribute__((ext_vector_type(8)));
typedef float f32x4 __attribute__((ext_vector_type(4)));

#define B_IMG 128
#define NOBJ  36
#define NNODE (B_IMG * NOBJ)

__device__ __forceinline__ float b2f(u16 u) {
    union { unsigned int i; float f; } v; v.i = ((unsigned int)u) << 16; return v.f;
}
__device__ __forceinline__ u16 f2b(float f) {
    union { float f; unsigned int i; } v; v.f = f;
    unsigned int u = v.i;
    return (u16)((u + 0x7fffu + ((u >> 16) & 1u)) >> 16);   // RNE
}

// ---------------------------------------------------------------------------
// 64x64 convert+transpose tile body: src [Rs, C] fp32 -> dst [C, Rd] bf16,
// rows k >= Rs zero-filled.  Reads 256 B/instr, writes 128 B/instr.
// ---------------------------------------------------------------------------
__device__ __forceinline__ void tr64_body(u16 (*tile)[65], const float* __restrict__ src,
                                          u16* __restrict__ dst, int Rs, int Rd, int C,
                                          int tb, int t)
{
    const int ntx = C >> 6;
    const int ty = tb / ntx, tx = tb - ty * ntx;
    const int bx = tx * 64, by = ty * 64;     // bx: src col / dst row; by: src row (k)
    const int x = t & 63, y = t >> 6;         // 64 x 4
    #pragma unroll
    for (int i = y; i < 64; i += 4) {
        const int k = by + i;
        tile[i][x] = (k < Rs) ? f2b(src[(size_t)k * C + bx + x]) : (u16)0;
    }
    __syncthreads();
    #pragma unroll
    for (int i = y; i < 64; i += 4)
        dst[(size_t)(bx + i) * Rd + by + x] = tile[x][i];
}

// ---------------------------------------------------------------------------
// Fused S0 prep (one launch): of pack | qe pad | WqT | WvT | W3T | W1T | W2T.
// Block ranges: [0,9216) of | [+1280) qe | [+1280) Wq | [+1024) Wv |
// [+640) W3 | [+512) W1 | [+256) W2.   Total 14208.
// ---------------------------------------------------------------------------
__global__ __launch_bounds__(256)
void prep_all(const float* __restrict__ of, u16* __restrict__ of_c,
              const float* __restrict__ qe, u16* __restrict__ qe_c,
              const float* __restrict__ Wq, u16* __restrict__ WqT,
              const float* __restrict__ Wv, u16* __restrict__ WvT,
              const float* __restrict__ W3, u16* __restrict__ W3T,
              const float* __restrict__ W1, u16* __restrict__ W1T,
              const float* __restrict__ W2, u16* __restrict__ W2T)
{
    __shared__ u16 tile[64][65];
    int b = blockIdx.x;
    const int t = threadIdx.x;
    if (b < 9216) {
        const int i = b * 256 + t;               // < 4608*2048/4 exactly
        const float4 f = ((const float4*)of)[i];
        ushort4 o; o.x = f2b(f.x); o.y = f2b(f.y); o.z = f2b(f.z); o.w = f2b(f.w);
        ((ushort4*)of_c)[i] = o;
        return;
    }
    b -= 9216;
    if (b < 1280) {
        const int i = b * 256 + t;               // < 128*2560 exactly
        const int r = i / 2560, c = i - r * 2560;
        qe_c[i] = (c < 2400) ? f2b(qe[r * 2400 + c]) : (u16)0;
        return;
    }
    b -= 1280;
    if (b < 1280) { tr64_body(tile, Wq, WqT, 2400, 2560, 2048, b, t); return; }
    b -= 1280;
    if (b < 1024) { tr64_body(tile, Wv, WvT, 2048, 2048, 2048, b, t); return; }
    b -= 1024;
    if (b < 640)  { tr64_body(tile, W3, W3T, 1024, 1024, 2560, b, t); return; }
    b -= 640;
    if (b < 512)  { tr64_body(tile, W1, W1T, 2048, 2048, 1024, b, t); return; }
    b -= 512;
    tr64_body(tile, W2, W2T, 1024, 1024, 1024, b, t);
}

// ---------------------------------------------------------------------------
// TN MFMA GEMM: C[M,N] = A[M,K] * Bt[N,K]^T   (bf16 in, fp32 acc)
// MEASURED-BEST r7/r10 structure: 128x128 tile, BK=32, 4 waves 2x2,
// 4x4 16x16x32 MFMA/iter, A+B via global_load_lds, 2 stages = 32 KB,
// vmcnt(0)+barrier/iter, bijective XCD block swizzle.  FROZEN.
// EPI: 1 = splitK fp32 partial, 2 = +bias then *qmul -> bf16, 0 = bf16.
// ---------------------------------------------------------------------------
template<int EPI>
__global__ __launch_bounds__(256, 4)
void gemm_tn(const u16* __restrict__ A, const u16* __restrict__ Bt,
             int M, int N, int K, int kLen,
             float* __restrict__ Cf, u16* __restrict__ Cb,
             const float* __restrict__ bias, const float* __restrict__ qmul)
{
    __shared__ __align__(16) u16 lds[2 * 8192];   // 32 KB

    const int t    = threadIdx.x;
    const int lane = t & 63;
    const int wave = t >> 6;
    const int wr = wave >> 1, wc = wave & 1;
    const int quad = lane >> 4, l16 = lane & 15;

    // XCD swizzle: contiguous chunk of the xy-grid per XCD (bijective: nxy%8==0)
    const int nxy = gridDim.x * gridDim.y;
    int bid = blockIdx.x + gridDim.x * blockIdx.y;
    const int cpx = nxy >> 3;
    bid = (bid & 7) * cpx + (bid >> 3);
    const int bx = bid % gridDim.x, by = bid / gridDim.x;

    const int rowBase = by * 128;
    const int colBase = bx * 128;
    const int k0 = blockIdx.z * kLen;

    // staging: wave w owns rows [w*32, w*32+32); 2 DMA chunks of 16 rows per matrix.
    const u16* gA0 = A  + (size_t)(rowBase + wave * 32 + (lane >> 2)) * K + k0 + (lane & 3) * 8;
    const u16* gA1 = gA0 + 16 * (size_t)K;
    const u16* gB0 = Bt + (size_t)(colBase + wave * 32 + (lane >> 2)) * K + k0 + (lane & 3) * 8;
    const u16* gB1 = gB0 + 16 * (size_t)K;
    const int ro = wave * 1024;   // 32 rows * 32 u16

    int afr[4], bfr[4];
    #pragma unroll
    for (int r = 0; r < 4; r++) afr[r] = (wr * 64 + r * 16 + l16) * 32 + quad * 8;
    #pragma unroll
    for (int c = 0; c < 4; c++) bfr[c] = 4096 + (wc * 64 + c * 16 + l16) * 32 + quad * 8;

    f32x4 acc[4][4];
    #pragma unroll
    for (int r = 0; r < 4; r++)
        #pragma unroll
        for (int c = 0; c < 4; c++)
            acc[r][c] = (f32x4){0.f, 0.f, 0.f, 0.f};

    auto gld = [](const u16* g, u16* s) {
        __builtin_amdgcn_global_load_lds(
            (const __attribute__((address_space(1))) void*)g,
            (__attribute__((address_space(3))) void*)s, 16, 0, 0);
    };
    auto dma_stage = [&](int it, int st) {
        const int kk = it * 32;
        const int bo = st * 8192;
        gld(gA0 + kk, &lds[bo + ro]);
        gld(gA1 + kk, &lds[bo + ro + 512]);
        gld(gB0 + kk, &lds[bo + 4096 + ro]);
        gld(gB1 + kk, &lds[bo + 4096 + ro + 512]);
    };

    const int nIter = kLen >> 5;   // kLen % 32 == 0 at all call sites
    dma_stage(0, 0);

    for (int it = 0; it < nIter; ++it) {
        asm volatile("s_waitcnt vmcnt(0)\n\ts_barrier" ::: "memory");
        if (it + 1 < nIter) dma_stage(it + 1, (it + 1) & 1);
        const int bo = (it & 1) * 8192;
        bf16x8 avf[4], bvf[4];
        #pragma unroll
        for (int r = 0; r < 4; r++) avf[r] = *(const bf16x8*)&lds[bo + afr[r]];
        #pragma unroll
        for (int c = 0; c < 4; c++) bvf[c] = *(const bf16x8*)&lds[bo + bfr[c]];
        #pragma unroll
        for (int r = 0; r < 4; r++)
            #pragma unroll
            for (int c = 0; c < 4; c++)
                acc[r][c] = __builtin_amdgcn_mfma_f32_16x16x32_bf16(avf[r], bvf[c], acc[r][c], 0, 0, 0);
    }

    // epilogue: D row = quad*4+reg, col = l16
    #pragma unroll
    for (int r = 0; r < 4; r++) {
        const int mBase = rowBase + wr * 64 + r * 16 + quad * 4;
        #pragma unroll
        for (int c = 0; c < 4; c++) {
            const int n = colBase + wc * 64 + c * 16 + l16;
            #pragma unroll
            for (int e = 0; e < 4; e++) {
                const int m = mBase + e;
                float v = acc[r][c][e];
                if (EPI == 1) {
                    Cf[((size_t)blockIdx.z * M + m) * N + n] = v;
                } else if (EPI == 2) {
                    v += bias[n];
                    v *= qmul[(size_t)(m / NOBJ) * N + n];
                    Cb[(size_t)m * N + n] = f2b(v);
                } else {
                    Cb[(size_t)m * N + n] = f2b(v);
                }
            }
        }
    }
}

// ---------------------------------------------------------------------------
__global__ __launch_bounds__(256)
void qcombine(const float* __restrict__ p, const float* __restrict__ bias,
              float* __restrict__ q, int MN, int S)
{
    const int i = blockIdx.x * 256 + threadIdx.x;
    float s = 0.f;
    for (int z = 0; z < S; z++) s += p[(size_t)z * MN + i];
    q[i] = s + bias[i & 2047];
}

// ---------------------------------------------------------------------------
// Fused attention per (image, head) — layers 1/2 (r10: uint4 hl reads).
// MODE 1: relu(agg+b) -> g (bf16);  MODE 2: relu(agg+b)+resid -> g
// ---------------------------------------------------------------------------
template<int H, int C, int MODE>
__global__ __launch_bounds__(256)
void attn_kernel(const u16* __restrict__ h, const float* __restrict__ a_src,
                 const float* __restrict__ a_dst, const float* __restrict__ bias,
                 const u16* __restrict__ resid, u16* __restrict__ outb)
{
    __shared__ __align__(16) u16 hl[36 * C];
    __shared__ float alpha[36 * 36];
    __shared__ float asl[36], adl[36];
    __shared__ float psum[36][8][2];
    const int b = blockIdx.y, hd = blockIdx.x;
    const int t = threadIdx.x;
    const int nb = b * NOBJ;
    constexpr int CH = C / 8;
    for (int e = t; e < 36 * CH; e += 256) {
        const int row = e / CH, col = (e - row * CH) * 8;
        *(uint4*)&hl[row * C + col] = *(const uint4*)&h[(size_t)(nb + row) * (H * C) + hd * C + col];
    }
    __syncthreads();
    constexpr int SEG = C / 8;
    for (int e = t; e < 36 * 8; e += 256) {
        const int n = e >> 3, sg = e & 7;
        const u16*   hp = &hl[n * C + sg * SEG];
        const float* as = a_src + hd * C + sg * SEG;
        const float* ad = a_dst + hd * C + sg * SEG;
        float s1 = 0.f, s2 = 0.f;
        #pragma unroll 8
        for (int i = 0; i < SEG; i++) {
            const float hv = b2f(hp[i]);
            s1 += hv * as[i]; s2 += hv * ad[i];
        }
        psum[n][sg][0] = s1; psum[n][sg][1] = s2;
    }
    __syncthreads();
    if (t < 36) {
        float s1 = 0.f, s2 = 0.f;
        #pragma unroll
        for (int sg = 0; sg < 8; sg++) { s1 += psum[t][sg][0]; s2 += psum[t][sg][1]; }
        asl[t] = s1; adl[t] = s2;
    }
    __syncthreads();
    if (t < 36) {
        const float ad = adl[t];
        float mx = -1e30f;
        for (int s = 0; s < 36; s++) {
            float v = asl[s] + ad; v = (v > 0.f) ? v : 0.2f * v;
            alpha[t * 36 + s] = v; mx = fmaxf(mx, v);
        }
        float sum = 0.f;
        for (int s = 0; s < 36; s++) { const float ex = expf(alpha[t * 36 + s] - mx); alpha[t * 36 + s] = ex; sum += ex; }
        const float inv = 1.f / (sum + 1e-16f);
        for (int s = 0; s < 36; s++) alpha[t * 36 + s] *= inv;
    }
    __syncthreads();
    constexpr int NC8 = C / 8;
    for (int e = t; e < 36 * NC8; e += 256) {
        const int d = e / NC8, c8 = (e - d * NC8) * 8;
        float a0 = 0, a1 = 0, a2 = 0, a3 = 0, a4 = 0, a5 = 0, a6 = 0, a7 = 0;
        for (int s = 0; s < 36; s++) {
            const float al = alpha[d * 36 + s];
            const uint4 hv = *(const uint4*)&hl[s * C + c8];
            a0 += al * b2f((u16)hv.x);  a1 += al * b2f((u16)(hv.x >> 16));
            a2 += al * b2f((u16)hv.y);  a3 += al * b2f((u16)(hv.y >> 16));
            a4 += al * b2f((u16)hv.z);  a5 += al * b2f((u16)(hv.z >> 16));
            a6 += al * b2f((u16)hv.w);  a7 += al * b2f((u16)(hv.w >> 16));
        }
        const int n = nb + d;
        const size_t base = (size_t)n * (H * C) + hd * C + c8;
        const int bb = hd * C + c8;
        float v0 = a0 + bias[bb + 0], v1 = a1 + bias[bb + 1];
        float v2 = a2 + bias[bb + 2], v3 = a3 + bias[bb + 3];
        float v4 = a4 + bias[bb + 4], v5 = a5 + bias[bb + 5];
        float v6 = a6 + bias[bb + 6], v7 = a7 + bias[bb + 7];
        v0 = v0 > 0.f ? v0 : 0.f; v1 = v1 > 0.f ? v1 : 0.f;
        v2 = v2 > 0.f ? v2 : 0.f; v3 = v3 > 0.f ? v3 : 0.f;
        v4 = v4 > 0.f ? v4 : 0.f; v5 = v5 > 0.f ? v5 : 0.f;
        v6 = v6 > 0.f ? v6 : 0.f; v7 = v7 > 0.f ? v7 : 0.f;
        if (MODE == 2) {
            const uint4 rv = *(const uint4*)&resid[base];
            v0 += b2f((u16)rv.x); v1 += b2f((u16)(rv.x >> 16));
            v2 += b2f((u16)rv.y); v3 += b2f((u16)(rv.y >> 16));
            v4 += b2f((u16)rv.z); v5 += b2f((u16)(rv.z >> 16));
            v6 += b2f((u16)rv.w); v7 += b2f((u16)(rv.w >> 16));
        }
        uint4 ov;
        ov.x = (unsigned)f2b(v0) | ((unsigned)f2b(v1) << 16);
        ov.y = (unsigned)f2b(v2) | ((unsigned)f2b(v3) << 16);
        ov.z = (unsigned)f2b(v4) | ((unsigned)f2b(v5) << 16);
        ov.w = (unsigned)f2b(v6) | ((unsigned)f2b(v7) << 16);
        *(uint4*)&outb[base] = ov;
    }
}

// ---------------------------------------------------------------------------
// Fused al + softmax per (head, image), layer 3 -> alphaG (0.2 mean folded).
// ---------------------------------------------------------------------------
template<int H, int C, bool MEAN>
__global__ __launch_bounds__(256)
void al_alpha(const u16* __restrict__ h, const float* __restrict__ a_s,
              const float* __restrict__ a_d, float* __restrict__ alphaG)
{
    __shared__ float asl[36], adl[36];
    const int hd = blockIdx.x, b = blockIdx.y;
    const int nb = b * NOBJ;
    const int t = threadIdx.x, wv = t >> 6, lane = t & 63;
    constexpr int PL = C / 64;
    const float* asp = a_s + hd * C + lane * PL;
    const float* adp = a_d + hd * C + lane * PL;
    for (int n = wv; n < 36; n += 4) {
        const u16* hp = h + (size_t)(nb + n) * (H * C) + hd * C + lane * PL;
        u16 hb[PL];
        if constexpr (PL == 4) { *(uint2*)hb = *(const uint2*)hp; }
        else                   { *(uint4*)hb = *(const uint4*)hp; }
        float s1 = 0.f, s2 = 0.f;
        #pragma unroll
        for (int i = 0; i < PL; i++) {
            const float hv = b2f(hb[i]);
            s1 += hv * asp[i];
            s2 += hv * adp[i];
        }
        #pragma unroll
        for (int off = 32; off > 0; off >>= 1) {
            s1 += __shfl_down(s1, off);
            s2 += __shfl_down(s2, off);
        }
        if (lane == 0) { asl[n] = s1; adl[n] = s2; }
    }
    __syncthreads();
    if (t >= 36) return;
    const float ad = adl[t];
    float row[36];
    float mx = -1e30f;
    #pragma unroll
    for (int s = 0; s < 36; s++) {
        float v = asl[s] + ad; v = (v > 0.f) ? v : 0.2f * v;
        row[s] = v; mx = fmaxf(mx, v);
    }
    float sum = 0.f;
    #pragma unroll
    for (int s = 0; s < 36; s++) { row[s] = expf(row[s] - mx); sum += row[s]; }
    const float inv = (MEAN ? 0.2f : 1.0f) / (sum + 1e-16f);
    float* o = alphaG + (((size_t)b * H + hd) * 36 + t) * 36;
    #pragma unroll
    for (int s = 0; s < 36; s++) o[s] = row[s] * inv;
}

// ---------------------------------------------------------------------------
// Aggregation, mean layer (3), v3: grid (8 slabs of 64 cols, B_IMG),
// 192 threads.  Thread t<144 owns a d-ROW-PAIR (d0=2*(t>>3), d1=d0+1) and
// one c8 = (t&7)*8: per s-iter ONE ds_read_b128 + 8 unpack feeds 16 FMA
// (was 34 ops/16 FMA in v2 -> 25).  Lanes 8-15 read the same hl addresses
// as lanes 0-7 (broadcast, free).  alpha loads vectorized float4 (2 rounds).
// 1024 blocks = 4/CU x 3 waves = 12 waves/CU; 16 acc -> ~55 VGPR.
// ---------------------------------------------------------------------------
__global__ __launch_bounds__(192)
void attn_agg_mean(const u16* __restrict__ h, const float* __restrict__ alphaG,
                   const float* __restrict__ bias3, float* __restrict__ outp)
{
    __shared__ __align__(16) u16 hl[36 * 64];
    __shared__ __align__(16) float al[36 * 36];
    const int b = blockIdx.y, sl = blockIdx.x;    // sl in [0,8)
    const int nb = b * NOBJ, cb = sl * 64;
    const int t = threadIdx.x;
    const int dp = t >> 3, c8 = (t & 7) * 8;      // valid when t < 144
    const int d0 = dp * 2, d1 = d0 + 1;

    float a00 = 0, a01 = 0, a02 = 0, a03 = 0, a04 = 0, a05 = 0, a06 = 0, a07 = 0;
    float a10 = 0, a11 = 0, a12 = 0, a13 = 0, a14 = 0, a15 = 0, a16 = 0, a17 = 0;

    for (int hd = 0; hd < 5; hd++) {
        if (hd) __syncthreads();   // protect hl/al overwrite
        // hl: 36 rows x 64 u16 = 288 uint4
        for (int e = t; e < 288; e += 192) {
            const int row = e >> 3, col = (e & 7) * 8;
            *(uint4*)&hl[row * 64 + col] =
                *(const uint4*)&h[(size_t)(nb + row) * 2560 + hd * 512 + cb + col];
        }
        // al: 1296 floats = 324 float4
        const float4* ap = (const float4*)(alphaG + ((size_t)b * 5 + hd) * 1296);
        for (int e = t; e < 324; e += 192) ((float4*)al)[e] = ap[e];
        __syncthreads();
        if (t < 144) {
            const float* ar0 = &al[d0 * 36];
            const float* ar1 = &al[d1 * 36];
            #pragma unroll
            for (int s = 0; s < 36; s++) {
                const uint4 hv = *(const uint4*)&hl[s * 64 + c8];
                const float f0 = b2f((u16)hv.x), f1 = b2f((u16)(hv.x >> 16));
                const float f2 = b2f((u16)hv.y), f3 = b2f((u16)(hv.y >> 16));
                const float f4 = b2f((u16)hv.z), f5 = b2f((u16)(hv.z >> 16));
                const float f6 = b2f((u16)hv.w), f7 = b2f((u16)(hv.w >> 16));
                const float av0 = ar0[s], av1 = ar1[s];
                a00 += av0 * f0; a01 += av0 * f1; a02 += av0 * f2; a03 += av0 * f3;
                a04 += av0 * f4; a05 += av0 * f5; a06 += av0 * f6; a07 += av0 * f7;
                a10 += av1 * f0; a11 += av1 * f1; a12 += av1 * f2; a13 += av1 * f3;
                a14 += av1 * f4; a15 += av1 * f5; a16 += av1 * f6; a17 += av1 * f7;
            }
        }
    }
    if (t < 144) {
        const float* bp = &bias3[cb + c8];
        const float b0 = bp[0], b1 = bp[1], b2 = bp[2], b3v = bp[3];
        const float b4 = bp[4], b5 = bp[5], b6 = bp[6], b7 = bp[7];
        float* op0 = &outp[(size_t)(nb + d0) * 512 + cb + c8];
        float* op1 = &outp[(size_t)(nb + d1) * 512 + cb + c8];
        float4 w;
        w.x = a00 + b0; w.y = a01 + b1; w.z = a02 + b2; w.w = a03 + b3v;
        *(float4*)op0 = w;
        w.x = a04 + b4; w.y = a05 + b5; w.z = a06 + b6; w.w = a07 + b7;
        *(float4*)(op0 + 4) = w;
        w.x = a10 + b0; w.y = a11 + b1; w.z = a12 + b2; w.w = a13 + b3v;
        *(float4*)op1 = w;
        w.x = a14 + b4; w.y = a15 + b5; w.z = a16 + b6; w.w = a17 + b7;
        *(float4*)(op1 + 4) = w;
    }
}

// ---------------------------------------------------------------------------
// Workspace ~73.5 MB, lifetime-packed:
//  E: qe_c 0.66M | of_c 18.87M
//  A (23.59M): WqT(10.49)+qpart(10.49 @ +10.49, splitK=10) -> x -> g1 -> h3
//  B ( 9.44M): WvT(8.39), q(1.05 @ +8.39) -> g2
//  C ( 9.44M): h1 -> h2
//  F ( 5.24M): W3T (S0 -> S11 read)  then  alphaG (S13 -> S14)   [union]
//  G ( 6.29M): W1T(4.19) + W2T(2.10)  (S0 -> S8 read)
// ---------------------------------------------------------------------------
extern "C" void kernel_launch(void* const* d_in, const int* in_sizes, int n_in,
                              void* d_out, int out_size, void* d_ws, size_t ws_size,
                              hipStream_t stream)
{
    const float* qe  = (const float*)d_in[0];    // [128,2400]
    const float* of  = (const float*)d_in[1];    // [4608,2048]
    const float* Wq  = (const float*)d_in[3];    // [2400,2048]
    const float* bq  = (const float*)d_in[4];
    const float* Wv  = (const float*)d_in[5];    // [2048,2048]
    const float* bv  = (const float*)d_in[6];
    const float* W1  = (const float*)d_in[7];    // [2048,1024]
    const float* a1s = (const float*)d_in[8];
    const float* a1d = (const float*)d_in[9];
    const float* b1  = (const float*)d_in[10];
    const float* W2  = (const float*)d_in[11];   // [1024,1024]
    const float* a2s = (const float*)d_in[12];
    const float* a2d = (const float*)d_in[13];
    const float* b2  = (const float*)d_in[14];
    const float* W3  = (const float*)d_in[15];   // [1024,2560]
    const float* a3s = (const float*)d_in[16];
    const float* a3d = (const float*)d_in[17];
    const float* b3  = (const float*)d_in[18];
    float* out = (float*)d_out;
    (void)ws_size; (void)in_sizes; (void)n_in; (void)out_size;

    char* W0 = (char*)d_ws;
    size_t off = 0;
    auto alloc = [&](size_t bytes) -> char* {
        char* p = W0 + off; off += (bytes + 255) & ~(size_t)255; return p;
    };
    u16* qe_c = (u16*)alloc(128ull * 2560 * 2);
    u16* of_c = (u16*)alloc(4608ull * 2048 * 2);
    const size_t szA = 4608ull * 2560 * 2;
    const size_t szB = 4608ull * 1024 * 2;
    const size_t szC = 4608ull * 1024 * 2;
    char* Abase = alloc(szA);
    char* Bbase = alloc(szB);
    char* Cbase = alloc(szC);
    char* Fbase = alloc(2560ull * 1024 * 2);   // 5.24 MB union: W3T then alphaG
    char* Gbase = alloc(1024ull * 2048 * 2 + 1024ull * 1024 * 2);  // W1T + W2T

    u16*   WqT   = (u16*)Abase;                           // [2048,2560]
    float* qpart = (float*)(Abase + 2048ull * 2560 * 2);  // 10 x 1.05 MB (splitK=10)
    u16*   x     = (u16*)Abase;
    u16*   g1    = (u16*)Abase;
    u16*   h3    = (u16*)Abase;
    u16*   WvT   = (u16*)Bbase;                           // [2048,2048]
    float* q     = (float*)(Bbase + 2048ull * 2048 * 2);
    u16*   g2    = (u16*)Bbase;
    u16*   h1    = (u16*)Cbase;
    u16*   h2    = (u16*)Cbase;
    u16*   W3T   = (u16*)Fbase;                           // [2560,1024], S0->S11
    float* alphaG = (float*)Fbase;                        // 3.32 MB, S13->S14
    u16*   W1T   = (u16*)Gbase;                           // [1024,2048]
    u16*   W2T   = (u16*)(Gbase + 1024ull * 2048 * 2);    // [1024,1024]

    // S0: ALL converts + ALL weight transposes in ONE launch
    prep_all<<<dim3(14208), 256, 0, stream>>>(of, of_c, qe, qe_c,
                                              Wq, WqT, Wv, WvT, W3, W3T,
                                              W1, W1T, W2, W2T);

    // S2-S3: q = qe @ Wq + bq   (splitK=10 x 256: 160 blocks)
    gemm_tn<1><<<dim3(16, 1, 10), 256, 0, stream>>>(qe_c, WqT, 128, 2048, 2560, 256,
                                                    qpart, nullptr, nullptr, nullptr);
    qcombine<<<dim3(128 * 2048 / 256), 256, 0, stream>>>(qpart, bq, q, 128 * 2048, 10);

    // S4: x = (of @ Wv + bv) * q_rep   (576 blocks — frozen best)
    gemm_tn<2><<<dim3(16, 36, 1), 256, 0, stream>>>(of_c, WvT, 4608, 2048, 2048, 2048,
                                                    nullptr, x, bv, q);

    // S6-S7: layer 1 (fused attention)
    gemm_tn<0><<<dim3(8, 36, 1), 256, 0, stream>>>(x, W1T, 4608, 1024, 2048, 2048,
                                                   nullptr, h1, nullptr, nullptr);
    attn_kernel<4, 256, 1><<<dim3(4, B_IMG), 256, 0, stream>>>(h1, a1s, a1d, b1, nullptr, g1);

    // S8-S9: layer 2 (+ residual g1, fused attention)
    gemm_tn<0><<<dim3(8, 36, 1), 256, 0, stream>>>(g1, W2T, 4608, 1024, 1024, 1024,
                                                   nullptr, h2, nullptr, nullptr);
    attn_kernel<4, 256, 2><<<dim3(4, B_IMG), 256, 0, stream>>>(h2, a2s, a2d, b2, g1, g2);

    // S11-S14: layer 3 (5 heads, mean + b3) -> fp32 out
    gemm_tn<0><<<dim3(20, 36, 1), 256, 0, stream>>>(g2, W3T, 4608, 2560, 1024, 1024,
                                                    nullptr, h3, nullptr, nullptr);
    al_alpha<5, 512, true><<<dim3(5, B_IMG), 256, 0, stream>>>(h3, a3s, a3d, alphaG);
    attn_agg_mean<<<dim3(8, B_IMG), 192, 0, stream>>>(h3, alphaG, b3, out);
}

// Round 15
// 407.826 us; speedup vs baseline: 1.1823x; 1.0144x over previous
//
#include <hip/hip_runtime.h>
#include <hip/hip_bf16.h>

typedef unsigned short u16;
typedef __bf16 bf16x8 __attribute__((ext_vector_type(8)));
typedef float f32x4 __attribute__((ext_vector_type(4)));

#define B_IMG 128
#define NOBJ  36
#define NNODE (B_IMG * NOBJ)

__device__ __forceinline__ float b2f(u16 u) {
    union { unsigned int i; float f; } v; v.i = ((unsigned int)u) << 16; return v.f;
}
__device__ __forceinline__ u16 f2b(float f) {
    union { float f; unsigned int i; } v; v.f = f;
    unsigned int u = v.i;
    return (u16)((u + 0x7fffu + ((u >> 16) & 1u)) >> 16);   // RNE
}

// ---------------------------------------------------------------------------
// 64x64 convert+transpose tile body: src [Rs, C] fp32 -> dst [C, Rd] bf16,
// rows k >= Rs zero-filled.  Reads 256 B/instr, writes 128 B/instr.
// ---------------------------------------------------------------------------
__device__ __forceinline__ void tr64_body(u16 (*tile)[65], const float* __restrict__ src,
                                          u16* __restrict__ dst, int Rs, int Rd, int C,
                                          int tb, int t)
{
    const int ntx = C >> 6;
    const int ty = tb / ntx, tx = tb - ty * ntx;
    const int bx = tx * 64, by = ty * 64;     // bx: src col / dst row; by: src row (k)
    const int x = t & 63, y = t >> 6;         // 64 x 4
    #pragma unroll
    for (int i = y; i < 64; i += 4) {
        const int k = by + i;
        tile[i][x] = (k < Rs) ? f2b(src[(size_t)k * C + bx + x]) : (u16)0;
    }
    __syncthreads();
    #pragma unroll
    for (int i = y; i < 64; i += 4)
        dst[(size_t)(bx + i) * Rd + by + x] = tile[x][i];
}

// ---------------------------------------------------------------------------
// Fused S0 prep (one launch): of pack | qe pad | WqT | WvT | W3T | W1T | W2T.
// Block ranges: [0,9216) of | [+1280) qe | [+1280) Wq | [+1024) Wv |
// [+640) W3 | [+512) W1 | [+256) W2.   Total 14208.
// ---------------------------------------------------------------------------
__global__ __launch_bounds__(256)
void prep_all(const float* __restrict__ of, u16* __restrict__ of_c,
              const float* __restrict__ qe, u16* __restrict__ qe_c,
              const float* __restrict__ Wq, u16* __restrict__ WqT,
              const float* __restrict__ Wv, u16* __restrict__ WvT,
              const float* __restrict__ W3, u16* __restrict__ W3T,
              const float* __restrict__ W1, u16* __restrict__ W1T,
              const float* __restrict__ W2, u16* __restrict__ W2T)
{
    __shared__ u16 tile[64][65];
    int b = blockIdx.x;
    const int t = threadIdx.x;
    if (b < 9216) {
        const int i = b * 256 + t;               // < 4608*2048/4 exactly
        const float4 f = ((const float4*)of)[i];
        ushort4 o; o.x = f2b(f.x); o.y = f2b(f.y); o.z = f2b(f.z); o.w = f2b(f.w);
        ((ushort4*)of_c)[i] = o;
        return;
    }
    b -= 9216;
    if (b < 1280) {
        const int i = b * 256 + t;               // < 128*2560 exactly
        const int r = i / 2560, c = i - r * 2560;
        qe_c[i] = (c < 2400) ? f2b(qe[r * 2400 + c]) : (u16)0;
        return;
    }
    b -= 1280;
    if (b < 1280) { tr64_body(tile, Wq, WqT, 2400, 2560, 2048, b, t); return; }
    b -= 1280;
    if (b < 1024) { tr64_body(tile, Wv, WvT, 2048, 2048, 2048, b, t); return; }
    b -= 1024;
    if (b < 640)  { tr64_body(tile, W3, W3T, 1024, 1024, 2560, b, t); return; }
    b -= 640;
    if (b < 512)  { tr64_body(tile, W1, W1T, 2048, 2048, 1024, b, t); return; }
    b -= 512;
    tr64_body(tile, W2, W2T, 1024, 1024, 1024, b, t);
}

// ---------------------------------------------------------------------------
// TN MFMA GEMM: C[M,N] = A[M,K] * Bt[N,K]^T   (bf16 in, fp32 acc)
// Frozen r7 schedule (2-stage, vmcnt(0)+barrier/iter, XCD swizzle) with BM
// parameter.  BM=128 (frozen best): S2/S4/S11, grids >= 2.25 blocks/CU.
// BM=64 ONLY for the grid-starved S6/S8 (were 288 blocks = 1.125/CU with
// no cross-block drain overlap): 576 blocks, 24 KB LDS -> 6 blocks/CU.
// Isolated test of the r0 occupancy mechanism (r12's BM=64 trial was
// confounded by the agg_mean regression).
// EPI: 1 = splitK fp32 partial, 2 = +bias then *qmul -> bf16, 0 = bf16.
// ---------------------------------------------------------------------------
template<int EPI, int BM>
__global__ __launch_bounds__(256, (BM == 64 ? 6 : 4))
void gemm_tn(const u16* __restrict__ A, const u16* __restrict__ Bt,
             int M, int N, int K, int kLen,
             float* __restrict__ Cf, u16* __restrict__ Cb,
             const float* __restrict__ bias, const float* __restrict__ qmul)
{
    constexpr int RF  = BM / 32;          // row frags per wave
    constexpr int ASZ = BM * 32;          // A stage size in u16
    constexpr int SS  = ASZ + 4096;       // stage stride in u16
    __shared__ __align__(16) u16 lds[2 * SS];

    const int t    = threadIdx.x;
    const int lane = t & 63;
    const int wave = t >> 6;
    const int wr = wave >> 1, wc = wave & 1;
    const int quad = lane >> 4, l16 = lane & 15;

    // XCD swizzle: contiguous chunk of the xy-grid per XCD (bijective: nxy%8==0)
    const int nxy = gridDim.x * gridDim.y;
    int bid = blockIdx.x + gridDim.x * blockIdx.y;
    const int cpx = nxy >> 3;
    bid = (bid & 7) * cpx + (bid >> 3);
    const int bx = bid % gridDim.x, by = bid / gridDim.x;

    const int rowBase = by * BM;
    const int colBase = bx * 128;
    const int k0 = blockIdx.z * kLen;

    // staging: wave w owns A rows [w*(BM/4), +BM/4) and B rows [w*32, +32).
    const u16* gA0 = A  + (size_t)(rowBase + wave * (BM / 4) + (lane >> 2)) * K + k0 + (lane & 3) * 8;
    const u16* gA1 = gA0 + 16 * (size_t)K;
    const u16* gB0 = Bt + (size_t)(colBase + wave * 32 + (lane >> 2)) * K + k0 + (lane & 3) * 8;
    const u16* gB1 = gB0 + 16 * (size_t)K;
    const int roA = wave * (BM / 4) * 32;
    const int roB = wave * 1024;

    int afr[RF], bfr[4];
    #pragma unroll
    for (int r = 0; r < RF; r++) afr[r] = (wr * (RF * 16) + r * 16 + l16) * 32 + quad * 8;
    #pragma unroll
    for (int c = 0; c < 4; c++) bfr[c] = ASZ + (wc * 64 + c * 16 + l16) * 32 + quad * 8;

    f32x4 acc[RF][4];
    #pragma unroll
    for (int r = 0; r < RF; r++)
        #pragma unroll
        for (int c = 0; c < 4; c++)
            acc[r][c] = (f32x4){0.f, 0.f, 0.f, 0.f};

    auto gld = [](const u16* g, u16* s) {
        __builtin_amdgcn_global_load_lds(
            (const __attribute__((address_space(1))) void*)g,
            (__attribute__((address_space(3))) void*)s, 16, 0, 0);
    };
    auto dma_stage = [&](int it, int st) {
        const int kk = it * 32;
        const int bo = st * SS;
        gld(gA0 + kk, &lds[bo + roA]);
        if constexpr (BM == 128) gld(gA1 + kk, &lds[bo + roA + 512]);
        gld(gB0 + kk, &lds[bo + ASZ + roB]);
        gld(gB1 + kk, &lds[bo + ASZ + roB + 512]);
    };

    const int nIter = kLen >> 5;   // kLen % 32 == 0 at all call sites
    dma_stage(0, 0);

    for (int it = 0; it < nIter; ++it) {
        asm volatile("s_waitcnt vmcnt(0)\n\ts_barrier" ::: "memory");
        if (it + 1 < nIter) dma_stage(it + 1, (it + 1) & 1);
        const int bo = (it & 1) * SS;
        bf16x8 avf[RF], bvf[4];
        #pragma unroll
        for (int r = 0; r < RF; r++) avf[r] = *(const bf16x8*)&lds[bo + afr[r]];
        #pragma unroll
        for (int c = 0; c < 4; c++) bvf[c] = *(const bf16x8*)&lds[bo + bfr[c]];
        #pragma unroll
        for (int r = 0; r < RF; r++)
            #pragma unroll
            for (int c = 0; c < 4; c++)
                acc[r][c] = __builtin_amdgcn_mfma_f32_16x16x32_bf16(avf[r], bvf[c], acc[r][c], 0, 0, 0);
    }

    // epilogue: D row = quad*4+reg, col = l16
    #pragma unroll
    for (int r = 0; r < RF; r++) {
        const int mBase = rowBase + wr * (RF * 16) + r * 16 + quad * 4;
        #pragma unroll
        for (int c = 0; c < 4; c++) {
            const int n = colBase + wc * 64 + c * 16 + l16;
            #pragma unroll
            for (int e = 0; e < 4; e++) {
                const int m = mBase + e;
                float v = acc[r][c][e];
                if (EPI == 1) {
                    Cf[((size_t)blockIdx.z * M + m) * N + n] = v;
                } else if (EPI == 2) {
                    v += bias[n];
                    v *= qmul[(size_t)(m / NOBJ) * N + n];
                    Cb[(size_t)m * N + n] = f2b(v);
                } else {
                    Cb[(size_t)m * N + n] = f2b(v);
                }
            }
        }
    }
}

// ---------------------------------------------------------------------------
__global__ __launch_bounds__(256)
void qcombine(const float* __restrict__ p, const float* __restrict__ bias,
              float* __restrict__ q, int MN, int S)
{
    const int i = blockIdx.x * 256 + threadIdx.x;
    float s = 0.f;
    for (int z = 0; z < S; z++) s += p[(size_t)z * MN + i];
    q[i] = s + bias[i & 2047];
}

// ---------------------------------------------------------------------------
// Fused attention per (image, head) — layers 1/2 (r10: uint4 hl reads).
// MODE 1: relu(agg+b) -> g (bf16);  MODE 2: relu(agg+b)+resid -> g
// ---------------------------------------------------------------------------
template<int H, int C, int MODE>
__global__ __launch_bounds__(256)
void attn_kernel(const u16* __restrict__ h, const float* __restrict__ a_src,
                 const float* __restrict__ a_dst, const float* __restrict__ bias,
                 const u16* __restrict__ resid, u16* __restrict__ outb)
{
    __shared__ __align__(16) u16 hl[36 * C];
    __shared__ float alpha[36 * 36];
    __shared__ float asl[36], adl[36];
    __shared__ float psum[36][8][2];
    const int b = blockIdx.y, hd = blockIdx.x;
    const int t = threadIdx.x;
    const int nb = b * NOBJ;
    constexpr int CH = C / 8;
    for (int e = t; e < 36 * CH; e += 256) {
        const int row = e / CH, col = (e - row * CH) * 8;
        *(uint4*)&hl[row * C + col] = *(const uint4*)&h[(size_t)(nb + row) * (H * C) + hd * C + col];
    }
    __syncthreads();
    constexpr int SEG = C / 8;
    for (int e = t; e < 36 * 8; e += 256) {
        const int n = e >> 3, sg = e & 7;
        const u16*   hp = &hl[n * C + sg * SEG];
        const float* as = a_src + hd * C + sg * SEG;
        const float* ad = a_dst + hd * C + sg * SEG;
        float s1 = 0.f, s2 = 0.f;
        #pragma unroll 8
        for (int i = 0; i < SEG; i++) {
            const float hv = b2f(hp[i]);
            s1 += hv * as[i]; s2 += hv * ad[i];
        }
        psum[n][sg][0] = s1; psum[n][sg][1] = s2;
    }
    __syncthreads();
    if (t < 36) {
        float s1 = 0.f, s2 = 0.f;
        #pragma unroll
        for (int sg = 0; sg < 8; sg++) { s1 += psum[t][sg][0]; s2 += psum[t][sg][1]; }
        asl[t] = s1; adl[t] = s2;
    }
    __syncthreads();
    if (t < 36) {
        const float ad = adl[t];
        float mx = -1e30f;
        for (int s = 0; s < 36; s++) {
            float v = asl[s] + ad; v = (v > 0.f) ? v : 0.2f * v;
            alpha[t * 36 + s] = v; mx = fmaxf(mx, v);
        }
        float sum = 0.f;
        for (int s = 0; s < 36; s++) { const float ex = expf(alpha[t * 36 + s] - mx); alpha[t * 36 + s] = ex; sum += ex; }
        const float inv = 1.f / (sum + 1e-16f);
        for (int s = 0; s < 36; s++) alpha[t * 36 + s] *= inv;
    }
    __syncthreads();
    constexpr int NC8 = C / 8;
    for (int e = t; e < 36 * NC8; e += 256) {
        const int d = e / NC8, c8 = (e - d * NC8) * 8;
        float a0 = 0, a1 = 0, a2 = 0, a3 = 0, a4 = 0, a5 = 0, a6 = 0, a7 = 0;
        for (int s = 0; s < 36; s++) {
            const float al = alpha[d * 36 + s];
            const uint4 hv = *(const uint4*)&hl[s * C + c8];
            a0 += al * b2f((u16)hv.x);  a1 += al * b2f((u16)(hv.x >> 16));
            a2 += al * b2f((u16)hv.y);  a3 += al * b2f((u16)(hv.y >> 16));
            a4 += al * b2f((u16)hv.z);  a5 += al * b2f((u16)(hv.z >> 16));
            a6 += al * b2f((u16)hv.w);  a7 += al * b2f((u16)(hv.w >> 16));
        }
        const int n = nb + d;
        const size_t base = (size_t)n * (H * C) + hd * C + c8;
        const int bb = hd * C + c8;
        float v0 = a0 + bias[bb + 0], v1 = a1 + bias[bb + 1];
        float v2 = a2 + bias[bb + 2], v3 = a3 + bias[bb + 3];
        float v4 = a4 + bias[bb + 4], v5 = a5 + bias[bb + 5];
        float v6 = a6 + bias[bb + 6], v7 = a7 + bias[bb + 7];
        v0 = v0 > 0.f ? v0 : 0.f; v1 = v1 > 0.f ? v1 : 0.f;
        v2 = v2 > 0.f ? v2 : 0.f; v3 = v3 > 0.f ? v3 : 0.f;
        v4 = v4 > 0.f ? v4 : 0.f; v5 = v5 > 0.f ? v5 : 0.f;
        v6 = v6 > 0.f ? v6 : 0.f; v7 = v7 > 0.f ? v7 : 0.f;
        if (MODE == 2) {
            const uint4 rv = *(const uint4*)&resid[base];
            v0 += b2f((u16)rv.x); v1 += b2f((u16)(rv.x >> 16));
            v2 += b2f((u16)rv.y); v3 += b2f((u16)(rv.y >> 16));
            v4 += b2f((u16)rv.z); v5 += b2f((u16)(rv.z >> 16));
            v6 += b2f((u16)rv.w); v7 += b2f((u16)(rv.w >> 16));
        }
        uint4 ov;
        ov.x = (unsigned)f2b(v0) | ((unsigned)f2b(v1) << 16);
        ov.y = (unsigned)f2b(v2) | ((unsigned)f2b(v3) << 16);
        ov.z = (unsigned)f2b(v4) | ((unsigned)f2b(v5) << 16);
        ov.w = (unsigned)f2b(v6) | ((unsigned)f2b(v7) << 16);
        *(uint4*)&outb[base] = ov;
    }
}

// ---------------------------------------------------------------------------
// Fused al + softmax per (head, image), layer 3 -> alphaG (0.2 mean folded).
// ---------------------------------------------------------------------------
template<int H, int C, bool MEAN>
__global__ __launch_bounds__(256)
void al_alpha(const u16* __restrict__ h, const float* __restrict__ a_s,
              const float* __restrict__ a_d, float* __restrict__ alphaG)
{
    __shared__ float asl[36], adl[36];
    const int hd = blockIdx.x, b = blockIdx.y;
    const int nb = b * NOBJ;
    const int t = threadIdx.x, wv = t >> 6, lane = t & 63;
    constexpr int PL = C / 64;
    const float* asp = a_s + hd * C + lane * PL;
    const float* adp = a_d + hd * C + lane * PL;
    for (int n = wv; n < 36; n += 4) {
        const u16* hp = h + (size_t)(nb + n) * (H * C) + hd * C + lane * PL;
        u16 hb[PL];
        if constexpr (PL == 4) { *(uint2*)hb = *(const uint2*)hp; }
        else                   { *(uint4*)hb = *(const uint4*)hp; }
        float s1 = 0.f, s2 = 0.f;
        #pragma unroll
        for (int i = 0; i < PL; i++) {
            const float hv = b2f(hb[i]);
            s1 += hv * asp[i];
            s2 += hv * adp[i];
        }
        #pragma unroll
        for (int off = 32; off > 0; off >>= 1) {
            s1 += __shfl_down(s1, off);
            s2 += __shfl_down(s2, off);
        }
        if (lane == 0) { asl[n] = s1; adl[n] = s2; }
    }
    __syncthreads();
    if (t >= 36) return;
    const float ad = adl[t];
    float row[36];
    float mx = -1e30f;
    #pragma unroll
    for (int s = 0; s < 36; s++) {
        float v = asl[s] + ad; v = (v > 0.f) ? v : 0.2f * v;
        row[s] = v; mx = fmaxf(mx, v);
    }
    float sum = 0.f;
    #pragma unroll
    for (int s = 0; s < 36; s++) { row[s] = expf(row[s] - mx); sum += row[s]; }
    const float inv = (MEAN ? 0.2f : 1.0f) / (sum + 1e-16f);
    float* o = alphaG + (((size_t)b * H + hd) * 36 + t) * 36;
    #pragma unroll
    for (int s = 0; s < 36; s++) o[s] = row[s] * inv;
}

// ---------------------------------------------------------------------------
// Aggregation, mean layer (3), v3 (r14 measured-good): grid (8, B_IMG),
// 192 threads; thread t<144 owns a d-row-pair + one c8; per s-iter ONE
// ds_read_b128 + 8 unpack feeds 16 FMA.
// ---------------------------------------------------------------------------
__global__ __launch_bounds__(192)
void attn_agg_mean(const u16* __restrict__ h, const float* __restrict__ alphaG,
                   const float* __restrict__ bias3, float* __restrict__ outp)
{
    __shared__ __align__(16) u16 hl[36 * 64];
    __shared__ __align__(16) float al[36 * 36];
    const int b = blockIdx.y, sl = blockIdx.x;    // sl in [0,8)
    const int nb = b * NOBJ, cb = sl * 64;
    const int t = threadIdx.x;
    const int dp = t >> 3, c8 = (t & 7) * 8;      // valid when t < 144
    const int d0 = dp * 2, d1 = d0 + 1;

    float a00 = 0, a01 = 0, a02 = 0, a03 = 0, a04 = 0, a05 = 0, a06 = 0, a07 = 0;
    float a10 = 0, a11 = 0, a12 = 0, a13 = 0, a14 = 0, a15 = 0, a16 = 0, a17 = 0;

    for (int hd = 0; hd < 5; hd++) {
        if (hd) __syncthreads();   // protect hl/al overwrite
        for (int e = t; e < 288; e += 192) {
            const int row = e >> 3, col = (e & 7) * 8;
            *(uint4*)&hl[row * 64 + col] =
                *(const uint4*)&h[(size_t)(nb + row) * 2560 + hd * 512 + cb + col];
        }
        const float4* ap = (const float4*)(alphaG + ((size_t)b * 5 + hd) * 1296);
        for (int e = t; e < 324; e += 192) ((float4*)al)[e] = ap[e];
        __syncthreads();
        if (t < 144) {
            const float* ar0 = &al[d0 * 36];
            const float* ar1 = &al[d1 * 36];
            #pragma unroll
            for (int s = 0; s < 36; s++) {
                const uint4 hv = *(const uint4*)&hl[s * 64 + c8];
                const float f0 = b2f((u16)hv.x), f1 = b2f((u16)(hv.x >> 16));
                const float f2 = b2f((u16)hv.y), f3 = b2f((u16)(hv.y >> 16));
                const float f4 = b2f((u16)hv.z), f5 = b2f((u16)(hv.z >> 16));
                const float f6 = b2f((u16)hv.w), f7 = b2f((u16)(hv.w >> 16));
                const float av0 = ar0[s], av1 = ar1[s];
                a00 += av0 * f0; a01 += av0 * f1; a02 += av0 * f2; a03 += av0 * f3;
                a04 += av0 * f4; a05 += av0 * f5; a06 += av0 * f6; a07 += av0 * f7;
                a10 += av1 * f0; a11 += av1 * f1; a12 += av1 * f2; a13 += av1 * f3;
                a14 += av1 * f4; a15 += av1 * f5; a16 += av1 * f6; a17 += av1 * f7;
            }
        }
    }
    if (t < 144) {
        const float* bp = &bias3[cb + c8];
        const float b0 = bp[0], b1 = bp[1], b2 = bp[2], b3v = bp[3];
        const float b4 = bp[4], b5 = bp[5], b6 = bp[6], b7 = bp[7];
        float* op0 = &outp[(size_t)(nb + d0) * 512 + cb + c8];
        float* op1 = &outp[(size_t)(nb + d1) * 512 + cb + c8];
        float4 w;
        w.x = a00 + b0; w.y = a01 + b1; w.z = a02 + b2; w.w = a03 + b3v;
        *(float4*)op0 = w;
        w.x = a04 + b4; w.y = a05 + b5; w.z = a06 + b6; w.w = a07 + b7;
        *(float4*)(op0 + 4) = w;
        w.x = a10 + b0; w.y = a11 + b1; w.z = a12 + b2; w.w = a13 + b3v;
        *(float4*)op1 = w;
        w.x = a14 + b4; w.y = a15 + b5; w.z = a16 + b6; w.w = a17 + b7;
        *(float4*)(op1 + 4) = w;
    }
}

// ---------------------------------------------------------------------------
// Workspace ~73.5 MB, lifetime-packed:
//  E: qe_c 0.66M | of_c 18.87M
//  A (23.59M): WqT(10.49)+qpart(10.49 @ +10.49, splitK=10) -> x -> g1 -> h3
//  B ( 9.44M): WvT(8.39), q(1.05 @ +8.39) -> g2
//  C ( 9.44M): h1 -> h2
//  F ( 5.24M): W3T (S0 -> S11 read)  then  alphaG (S13 -> S14)   [union]
//  G ( 6.29M): W1T(4.19) + W2T(2.10)  (S0 -> S8 read)
// ---------------------------------------------------------------------------
extern "C" void kernel_launch(void* const* d_in, const int* in_sizes, int n_in,
                              void* d_out, int out_size, void* d_ws, size_t ws_size,
                              hipStream_t stream)
{
    const float* qe  = (const float*)d_in[0];    // [128,2400]
    const float* of  = (const float*)d_in[1];    // [4608,2048]
    const float* Wq  = (const float*)d_in[3];    // [2400,2048]
    const float* bq  = (const float*)d_in[4];
    const float* Wv  = (const float*)d_in[5];    // [2048,2048]
    const float* bv  = (const float*)d_in[6];
    const float* W1  = (const float*)d_in[7];    // [2048,1024]
    const float* a1s = (const float*)d_in[8];
    const float* a1d = (const float*)d_in[9];
    const float* b1  = (const float*)d_in[10];
    const float* W2  = (const float*)d_in[11];   // [1024,1024]
    const float* a2s = (const float*)d_in[12];
    const float* a2d = (const float*)d_in[13];
    const float* b2  = (const float*)d_in[14];
    const float* W3  = (const float*)d_in[15];   // [1024,2560]
    const float* a3s = (const float*)d_in[16];
    const float* a3d = (const float*)d_in[17];
    const float* b3  = (const float*)d_in[18];
    float* out = (float*)d_out;
    (void)ws_size; (void)in_sizes; (void)n_in; (void)out_size;

    char* W0 = (char*)d_ws;
    size_t off = 0;
    auto alloc = [&](size_t bytes) -> char* {
        char* p = W0 + off; off += (bytes + 255) & ~(size_t)255; return p;
    };
    u16* qe_c = (u16*)alloc(128ull * 2560 * 2);
    u16* of_c = (u16*)alloc(4608ull * 2048 * 2);
    const size_t szA = 4608ull * 2560 * 2;
    const size_t szB = 4608ull * 1024 * 2;
    const size_t szC = 4608ull * 1024 * 2;
    char* Abase = alloc(szA);
    char* Bbase = alloc(szB);
    char* Cbase = alloc(szC);
    char* Fbase = alloc(2560ull * 1024 * 2);   // 5.24 MB union: W3T then alphaG
    char* Gbase = alloc(1024ull * 2048 * 2 + 1024ull * 1024 * 2);  // W1T + W2T

    u16*   WqT   = (u16*)Abase;                           // [2048,2560]
    float* qpart = (float*)(Abase + 2048ull * 2560 * 2);  // 10 x 1.05 MB (splitK=10)
    u16*   x     = (u16*)Abase;
    u16*   g1    = (u16*)Abase;
    u16*   h3    = (u16*)Abase;
    u16*   WvT   = (u16*)Bbase;                           // [2048,2048]
    float* q     = (float*)(Bbase + 2048ull * 2048 * 2);
    u16*   g2    = (u16*)Bbase;
    u16*   h1    = (u16*)Cbase;
    u16*   h2    = (u16*)Cbase;
    u16*   W3T   = (u16*)Fbase;                           // [2560,1024], S0->S11
    float* alphaG = (float*)Fbase;                        // 3.32 MB, S13->S14
    u16*   W1T   = (u16*)Gbase;                           // [1024,2048]
    u16*   W2T   = (u16*)(Gbase + 1024ull * 2048 * 2);    // [1024,1024]

    // S0: ALL converts + ALL weight transposes in ONE launch
    prep_all<<<dim3(14208), 256, 0, stream>>>(of, of_c, qe, qe_c,
                                              Wq, WqT, Wv, WvT, W3, W3T,
                                              W1, W1T, W2, W2T);

    // S2-S3: q = qe @ Wq + bq   (splitK=10 x 256: 160 blocks)
    gemm_tn<1, 128><<<dim3(16, 1, 10), 256, 0, stream>>>(qe_c, WqT, 128, 2048, 2560, 256,
                                                         qpart, nullptr, nullptr, nullptr);
    qcombine<<<dim3(128 * 2048 / 256), 256, 0, stream>>>(qpart, bq, q, 128 * 2048, 10);

    // S4: x = (of @ Wv + bv) * q_rep   (576 blocks — frozen best)
    gemm_tn<2, 128><<<dim3(16, 36, 1), 256, 0, stream>>>(of_c, WvT, 4608, 2048, 2048, 2048,
                                                         nullptr, x, bv, q);

    // S6-S7: layer 1   (BM=64 -> 576 blocks, 6 blocks/CU: isolated test)
    gemm_tn<0, 64><<<dim3(8, 72, 1), 256, 0, stream>>>(x, W1T, 4608, 1024, 2048, 2048,
                                                       nullptr, h1, nullptr, nullptr);
    attn_kernel<4, 256, 1><<<dim3(4, B_IMG), 256, 0, stream>>>(h1, a1s, a1d, b1, nullptr, g1);

    // S8-S9: layer 2 (+ residual g1)   (BM=64 -> 576 blocks)
    gemm_tn<0, 64><<<dim3(8, 72, 1), 256, 0, stream>>>(g1, W2T, 4608, 1024, 1024, 1024,
                                                       nullptr, h2, nullptr, nullptr);
    attn_kernel<4, 256, 2><<<dim3(4, B_IMG), 256, 0, stream>>>(h2, a2s, a2d, b2, g1, g2);

    // S11-S14: layer 3 (5 heads, mean + b3) -> fp32 out   (BM=128, 720 blocks)
    gemm_tn<0, 128><<<dim3(20, 36, 1), 256, 0, stream>>>(g2, W3T, 4608, 2560, 1024, 1024,
                                                         nullptr, h3, nullptr, nullptr);
    al_alpha<5, 512, true><<<dim3(5, B_IMG), 256, 0, stream>>>(h3, a3s, a3d, alphaG);
    attn_agg_mean<<<dim3(8, B_IMG), 192, 0, stream>>>(h3, alphaG, b3, out);
}

// Round 16
// 403.506 us; speedup vs baseline: 1.1950x; 1.0107x over previous
//
#include <hip/hip_runtime.h>
#include <hip/hip_bf16.h>

typedef unsigned short u16;
typedef __bf16 bf16x8 __attribute__((ext_vector_type(8)));
typedef float f32x4 __attribute__((ext_vector_type(4)));

#define B_IMG 128
#define NOBJ  36
#define NNODE (B_IMG * NOBJ)

__device__ __forceinline__ float b2f(u16 u) {
    union { unsigned int i; float f; } v; v.i = ((unsigned int)u) << 16; return v.f;
}
__device__ __forceinline__ u16 f2b(float f) {
    union { float f; unsigned int i; } v; v.f = f;
    unsigned int u = v.i;
    return (u16)((u + 0x7fffu + ((u >> 16) & 1u)) >> 16);   // RNE
}

// ---------------------------------------------------------------------------
// 64x64 convert+transpose tile body: src [Rs, C] fp32 -> dst [C, Rd] bf16,
// rows k >= Rs zero-filled.  Reads 256 B/instr, writes 128 B/instr.
// ---------------------------------------------------------------------------
__device__ __forceinline__ void tr64_body(u16 (*tile)[65], const float* __restrict__ src,
                                          u16* __restrict__ dst, int Rs, int Rd, int C,
                                          int tb, int t)
{
    const int ntx = C >> 6;
    const int ty = tb / ntx, tx = tb - ty * ntx;
    const int bx = tx * 64, by = ty * 64;     // bx: src col / dst row; by: src row (k)
    const int x = t & 63, y = t >> 6;         // 64 x 4
    #pragma unroll
    for (int i = y; i < 64; i += 4) {
        const int k = by + i;
        tile[i][x] = (k < Rs) ? f2b(src[(size_t)k * C + bx + x]) : (u16)0;
    }
    __syncthreads();
    #pragma unroll
    for (int i = y; i < 64; i += 4)
        dst[(size_t)(bx + i) * Rd + by + x] = tile[x][i];
}

// ---------------------------------------------------------------------------
// Fused S0 prep (one launch): of pack | qe pad | WqT | WvT | W3T | W1T | W2T.
// Block ranges: [0,9216) of | [+1280) qe | [+1280) Wq | [+1024) Wv |
// [+640) W3 | [+512) W1 | [+256) W2.   Total 14208.
// ---------------------------------------------------------------------------
__global__ __launch_bounds__(256)
void prep_all(const float* __restrict__ of, u16* __restrict__ of_c,
              const float* __restrict__ qe, u16* __restrict__ qe_c,
              const float* __restrict__ Wq, u16* __restrict__ WqT,
              const float* __restrict__ Wv, u16* __restrict__ WvT,
              const float* __restrict__ W3, u16* __restrict__ W3T,
              const float* __restrict__ W1, u16* __restrict__ W1T,
              const float* __restrict__ W2, u16* __restrict__ W2T)
{
    __shared__ u16 tile[64][65];
    int b = blockIdx.x;
    const int t = threadIdx.x;
    if (b < 9216) {
        const int i = b * 256 + t;               // < 4608*2048/4 exactly
        const float4 f = ((const float4*)of)[i];
        ushort4 o; o.x = f2b(f.x); o.y = f2b(f.y); o.z = f2b(f.z); o.w = f2b(f.w);
        ((ushort4*)of_c)[i] = o;
        return;
    }
    b -= 9216;
    if (b < 1280) {
        const int i = b * 256 + t;               // < 128*2560 exactly
        const int r = i / 2560, c = i - r * 2560;
        qe_c[i] = (c < 2400) ? f2b(qe[r * 2400 + c]) : (u16)0;
        return;
    }
    b -= 1280;
    if (b < 1280) { tr64_body(tile, Wq, WqT, 2400, 2560, 2048, b, t); return; }
    b -= 1280;
    if (b < 1024) { tr64_body(tile, Wv, WvT, 2048, 2048, 2048, b, t); return; }
    b -= 1024;
    if (b < 640)  { tr64_body(tile, W3, W3T, 1024, 1024, 2560, b, t); return; }
    b -= 640;
    if (b < 512)  { tr64_body(tile, W1, W1T, 2048, 2048, 1024, b, t); return; }
    b -= 512;
    tr64_body(tile, W2, W2T, 1024, 1024, 1024, b, t);
}

// ---------------------------------------------------------------------------
// TN MFMA GEMM: C[M,N] = A[M,K] * Bt[N,K]^T   (bf16 in, fp32 acc)
// Frozen r7 schedule (2-stage, vmcnt(0)+barrier/iter, XCD swizzle) with BM
// parameter.  BM=128: S2/S4/S11.  BM=64: S6/S8 (r15 measured: -6us total,
// grid-starvation fix confirmed).  FROZEN.
// EPI: 1 = splitK fp32 partial, 2 = +bias then *qmul -> bf16, 0 = bf16.
// ---------------------------------------------------------------------------
template<int EPI, int BM>
__global__ __launch_bounds__(256, (BM == 64 ? 6 : 4))
void gemm_tn(const u16* __restrict__ A, const u16* __restrict__ Bt,
             int M, int N, int K, int kLen,
             float* __restrict__ Cf, u16* __restrict__ Cb,
             const float* __restrict__ bias, const float* __restrict__ qmul)
{
    constexpr int RF  = BM / 32;          // row frags per wave
    constexpr int ASZ = BM * 32;          // A stage size in u16
    constexpr int SS  = ASZ + 4096;       // stage stride in u16
    __shared__ __align__(16) u16 lds[2 * SS];

    const int t    = threadIdx.x;
    const int lane = t & 63;
    const int wave = t >> 6;
    const int wr = wave >> 1, wc = wave & 1;
    const int quad = lane >> 4, l16 = lane & 15;

    // XCD swizzle: contiguous chunk of the xy-grid per XCD (bijective: nxy%8==0)
    const int nxy = gridDim.x * gridDim.y;
    int bid = blockIdx.x + gridDim.x * blockIdx.y;
    const int cpx = nxy >> 3;
    bid = (bid & 7) * cpx + (bid >> 3);
    const int bx = bid % gridDim.x, by = bid / gridDim.x;

    const int rowBase = by * BM;
    const int colBase = bx * 128;
    const int k0 = blockIdx.z * kLen;

    // staging: wave w owns A rows [w*(BM/4), +BM/4) and B rows [w*32, +32).
    const u16* gA0 = A  + (size_t)(rowBase + wave * (BM / 4) + (lane >> 2)) * K + k0 + (lane & 3) * 8;
    const u16* gA1 = gA0 + 16 * (size_t)K;
    const u16* gB0 = Bt + (size_t)(colBase + wave * 32 + (lane >> 2)) * K + k0 + (lane & 3) * 8;
    const u16* gB1 = gB0 + 16 * (size_t)K;
    const int roA = wave * (BM / 4) * 32;
    const int roB = wave * 1024;

    int afr[RF], bfr[4];
    #pragma unroll
    for (int r = 0; r < RF; r++) afr[r] = (wr * (RF * 16) + r * 16 + l16) * 32 + quad * 8;
    #pragma unroll
    for (int c = 0; c < 4; c++) bfr[c] = ASZ + (wc * 64 + c * 16 + l16) * 32 + quad * 8;

    f32x4 acc[RF][4];
    #pragma unroll
    for (int r = 0; r < RF; r++)
        #pragma unroll
        for (int c = 0; c < 4; c++)
            acc[r][c] = (f32x4){0.f, 0.f, 0.f, 0.f};

    auto gld = [](const u16* g, u16* s) {
        __builtin_amdgcn_global_load_lds(
            (const __attribute__((address_space(1))) void*)g,
            (__attribute__((address_space(3))) void*)s, 16, 0, 0);
    };
    auto dma_stage = [&](int it, int st) {
        const int kk = it * 32;
        const int bo = st * SS;
        gld(gA0 + kk, &lds[bo + roA]);
        if constexpr (BM == 128) gld(gA1 + kk, &lds[bo + roA + 512]);
        gld(gB0 + kk, &lds[bo + ASZ + roB]);
        gld(gB1 + kk, &lds[bo + ASZ + roB + 512]);
    };

    const int nIter = kLen >> 5;   // kLen % 32 == 0 at all call sites
    dma_stage(0, 0);

    for (int it = 0; it < nIter; ++it) {
        asm volatile("s_waitcnt vmcnt(0)\n\ts_barrier" ::: "memory");
        if (it + 1 < nIter) dma_stage(it + 1, (it + 1) & 1);
        const int bo = (it & 1) * SS;
        bf16x8 avf[RF], bvf[4];
        #pragma unroll
        for (int r = 0; r < RF; r++) avf[r] = *(const bf16x8*)&lds[bo + afr[r]];
        #pragma unroll
        for (int c = 0; c < 4; c++) bvf[c] = *(const bf16x8*)&lds[bo + bfr[c]];
        #pragma unroll
        for (int r = 0; r < RF; r++)
            #pragma unroll
            for (int c = 0; c < 4; c++)
                acc[r][c] = __builtin_amdgcn_mfma_f32_16x16x32_bf16(avf[r], bvf[c], acc[r][c], 0, 0, 0);
    }

    // epilogue: D row = quad*4+reg, col = l16
    #pragma unroll
    for (int r = 0; r < RF; r++) {
        const int mBase = rowBase + wr * (RF * 16) + r * 16 + quad * 4;
        #pragma unroll
        for (int c = 0; c < 4; c++) {
            const int n = colBase + wc * 64 + c * 16 + l16;
            #pragma unroll
            for (int e = 0; e < 4; e++) {
                const int m = mBase + e;
                float v = acc[r][c][e];
                if (EPI == 1) {
                    Cf[((size_t)blockIdx.z * M + m) * N + n] = v;
                } else if (EPI == 2) {
                    v += bias[n];
                    v *= qmul[(size_t)(m / NOBJ) * N + n];
                    Cb[(size_t)m * N + n] = f2b(v);
                } else {
                    Cb[(size_t)m * N + n] = f2b(v);
                }
            }
        }
    }
}

// ---------------------------------------------------------------------------
__global__ __launch_bounds__(256)
void qcombine(const float* __restrict__ p, const float* __restrict__ bias,
              float* __restrict__ q, int MN, int S)
{
    const int i = blockIdx.x * 256 + threadIdx.x;
    float s = 0.f;
    for (int z = 0; z < S; z++) s += p[(size_t)z * MN + i];
    q[i] = s + bias[i & 2047];
}

// ---------------------------------------------------------------------------
// Fused attention per (image, head) — layers 1/2.  v2 aggregation: thread
// owns a d-ROW-PAIR (d0=2dp, d1=d0+1) and one c8 — per s-iter ONE
// ds_read_b128 + 8 unpack feeds 16 FMA (r14's proven agg_mean pattern;
// inner-op count -25%).  576 pair-items over 256 threads.
// MODE 1: relu(agg+b) -> g (bf16);  MODE 2: relu(agg+b)+resid -> g
// ---------------------------------------------------------------------------
template<int H, int C, int MODE>
__global__ __launch_bounds__(256)
void attn_kernel(const u16* __restrict__ h, const float* __restrict__ a_src,
                 const float* __restrict__ a_dst, const float* __restrict__ bias,
                 const u16* __restrict__ resid, u16* __restrict__ outb)
{
    __shared__ __align__(16) u16 hl[36 * C];
    __shared__ float alpha[36 * 36];
    __shared__ float asl[36], adl[36];
    __shared__ float psum[36][8][2];
    const int b = blockIdx.y, hd = blockIdx.x;
    const int t = threadIdx.x;
    const int nb = b * NOBJ;
    constexpr int CH = C / 8;
    for (int e = t; e < 36 * CH; e += 256) {
        const int row = e / CH, col = (e - row * CH) * 8;
        *(uint4*)&hl[row * C + col] = *(const uint4*)&h[(size_t)(nb + row) * (H * C) + hd * C + col];
    }
    __syncthreads();
    constexpr int SEG = C / 8;
    for (int e = t; e < 36 * 8; e += 256) {
        const int n = e >> 3, sg = e & 7;
        const u16*   hp = &hl[n * C + sg * SEG];
        const float* as = a_src + hd * C + sg * SEG;
        const float* ad = a_dst + hd * C + sg * SEG;
        float s1 = 0.f, s2 = 0.f;
        #pragma unroll 8
        for (int i = 0; i < SEG; i++) {
            const float hv = b2f(hp[i]);
            s1 += hv * as[i]; s2 += hv * ad[i];
        }
        psum[n][sg][0] = s1; psum[n][sg][1] = s2;
    }
    __syncthreads();
    if (t < 36) {
        float s1 = 0.f, s2 = 0.f;
        #pragma unroll
        for (int sg = 0; sg < 8; sg++) { s1 += psum[t][sg][0]; s2 += psum[t][sg][1]; }
        asl[t] = s1; adl[t] = s2;
    }
    __syncthreads();
    if (t < 36) {
        const float ad = adl[t];
        float mx = -1e30f;
        for (int s = 0; s < 36; s++) {
            float v = asl[s] + ad; v = (v > 0.f) ? v : 0.2f * v;
            alpha[t * 36 + s] = v; mx = fmaxf(mx, v);
        }
        float sum = 0.f;
        for (int s = 0; s < 36; s++) { const float ex = expf(alpha[t * 36 + s] - mx); alpha[t * 36 + s] = ex; sum += ex; }
        const float inv = 1.f / (sum + 1e-16f);
        for (int s = 0; s < 36; s++) alpha[t * 36 + s] *= inv;
    }
    __syncthreads();
    // aggregation: pair-items (dp, c8): 18 * (C/8) items
    constexpr int NC8 = C / 8;
    for (int e = t; e < 18 * NC8; e += 256) {
        const int dp = e / NC8, c8 = (e - dp * NC8) * 8;
        const int d0 = dp * 2, d1 = d0 + 1;
        float a00 = 0, a01 = 0, a02 = 0, a03 = 0, a04 = 0, a05 = 0, a06 = 0, a07 = 0;
        float a10 = 0, a11 = 0, a12 = 0, a13 = 0, a14 = 0, a15 = 0, a16 = 0, a17 = 0;
        const float* ar0 = &alpha[d0 * 36];
        const float* ar1 = &alpha[d1 * 36];
        for (int s = 0; s < 36; s++) {
            const uint4 hv = *(const uint4*)&hl[s * C + c8];
            const float f0 = b2f((u16)hv.x), f1 = b2f((u16)(hv.x >> 16));
            const float f2 = b2f((u16)hv.y), f3 = b2f((u16)(hv.y >> 16));
            const float f4 = b2f((u16)hv.z), f5 = b2f((u16)(hv.z >> 16));
            const float f6 = b2f((u16)hv.w), f7 = b2f((u16)(hv.w >> 16));
            const float av0 = ar0[s], av1 = ar1[s];
            a00 += av0 * f0; a01 += av0 * f1; a02 += av0 * f2; a03 += av0 * f3;
            a04 += av0 * f4; a05 += av0 * f5; a06 += av0 * f6; a07 += av0 * f7;
            a10 += av1 * f0; a11 += av1 * f1; a12 += av1 * f2; a13 += av1 * f3;
            a14 += av1 * f4; a15 += av1 * f5; a16 += av1 * f6; a17 += av1 * f7;
        }
        const int bb = hd * C + c8;
        const float bi0 = bias[bb + 0], bi1 = bias[bb + 1], bi2 = bias[bb + 2], bi3 = bias[bb + 3];
        const float bi4 = bias[bb + 4], bi5 = bias[bb + 5], bi6 = bias[bb + 6], bi7 = bias[bb + 7];
        #pragma unroll
        for (int rr = 0; rr < 2; rr++) {
            const int d = (rr == 0) ? d0 : d1;
            float v0 = (rr == 0 ? a00 : a10) + bi0, v1 = (rr == 0 ? a01 : a11) + bi1;
            float v2 = (rr == 0 ? a02 : a12) + bi2, v3 = (rr == 0 ? a03 : a13) + bi3;
            float v4 = (rr == 0 ? a04 : a14) + bi4, v5 = (rr == 0 ? a05 : a15) + bi5;
            float v6 = (rr == 0 ? a06 : a16) + bi6, v7 = (rr == 0 ? a07 : a17) + bi7;
            v0 = v0 > 0.f ? v0 : 0.f; v1 = v1 > 0.f ? v1 : 0.f;
            v2 = v2 > 0.f ? v2 : 0.f; v3 = v3 > 0.f ? v3 : 0.f;
            v4 = v4 > 0.f ? v4 : 0.f; v5 = v5 > 0.f ? v5 : 0.f;
            v6 = v6 > 0.f ? v6 : 0.f; v7 = v7 > 0.f ? v7 : 0.f;
            const size_t base = (size_t)(nb + d) * (H * C) + hd * C + c8;
            if (MODE == 2) {
                const uint4 rv = *(const uint4*)&resid[base];
                v0 += b2f((u16)rv.x); v1 += b2f((u16)(rv.x >> 16));
                v2 += b2f((u16)rv.y); v3 += b2f((u16)(rv.y >> 16));
                v4 += b2f((u16)rv.z); v5 += b2f((u16)(rv.z >> 16));
                v6 += b2f((u16)rv.w); v7 += b2f((u16)(rv.w >> 16));
            }
            uint4 ov;
            ov.x = (unsigned)f2b(v0) | ((unsigned)f2b(v1) << 16);
            ov.y = (unsigned)f2b(v2) | ((unsigned)f2b(v3) << 16);
            ov.z = (unsigned)f2b(v4) | ((unsigned)f2b(v5) << 16);
            ov.w = (unsigned)f2b(v6) | ((unsigned)f2b(v7) << 16);
            *(uint4*)&outb[base] = ov;
        }
    }
}

// ---------------------------------------------------------------------------
// Fused al + softmax per (head, image), layer 3 -> alphaG (0.2 mean folded).
// ---------------------------------------------------------------------------
template<int H, int C, bool MEAN>
__global__ __launch_bounds__(256)
void al_alpha(const u16* __restrict__ h, const float* __restrict__ a_s,
              const float* __restrict__ a_d, float* __restrict__ alphaG)
{
    __shared__ float asl[36], adl[36];
    const int hd = blockIdx.x, b = blockIdx.y;
    const int nb = b * NOBJ;
    const int t = threadIdx.x, wv = t >> 6, lane = t & 63;
    constexpr int PL = C / 64;
    const float* asp = a_s + hd * C + lane * PL;
    const float* adp = a_d + hd * C + lane * PL;
    for (int n = wv; n < 36; n += 4) {
        const u16* hp = h + (size_t)(nb + n) * (H * C) + hd * C + lane * PL;
        u16 hb[PL];
        if constexpr (PL == 4) { *(uint2*)hb = *(const uint2*)hp; }
        else                   { *(uint4*)hb = *(const uint4*)hp; }
        float s1 = 0.f, s2 = 0.f;
        #pragma unroll
        for (int i = 0; i < PL; i++) {
            const float hv = b2f(hb[i]);
            s1 += hv * asp[i];
            s2 += hv * adp[i];
        }
        #pragma unroll
        for (int off = 32; off > 0; off >>= 1) {
            s1 += __shfl_down(s1, off);
            s2 += __shfl_down(s2, off);
        }
        if (lane == 0) { asl[n] = s1; adl[n] = s2; }
    }
    __syncthreads();
    if (t >= 36) return;
    const float ad = adl[t];
    float row[36];
    float mx = -1e30f;
    #pragma unroll
    for (int s = 0; s < 36; s++) {
        float v = asl[s] + ad; v = (v > 0.f) ? v : 0.2f * v;
        row[s] = v; mx = fmaxf(mx, v);
    }
    float sum = 0.f;
    #pragma unroll
    for (int s = 0; s < 36; s++) { row[s] = expf(row[s] - mx); sum += row[s]; }
    const float inv = (MEAN ? 0.2f : 1.0f) / (sum + 1e-16f);
    float* o = alphaG + (((size_t)b * H + hd) * 36 + t) * 36;
    #pragma unroll
    for (int s = 0; s < 36; s++) o[s] = row[s] * inv;
}

// ---------------------------------------------------------------------------
// Aggregation, mean layer (3), v3 (r14 measured-good): grid (8, B_IMG),
// 192 threads; thread t<144 owns a d-row-pair + one c8; per s-iter ONE
// ds_read_b128 + 8 unpack feeds 16 FMA.
// ---------------------------------------------------------------------------
__global__ __launch_bounds__(192)
void attn_agg_mean(const u16* __restrict__ h, const float* __restrict__ alphaG,
                   const float* __restrict__ bias3, float* __restrict__ outp)
{
    __shared__ __align__(16) u16 hl[36 * 64];
    __shared__ __align__(16) float al[36 * 36];
    const int b = blockIdx.y, sl = blockIdx.x;    // sl in [0,8)
    const int nb = b * NOBJ, cb = sl * 64;
    const int t = threadIdx.x;
    const int dp = t >> 3, c8 = (t & 7) * 8;      // valid when t < 144
    const int d0 = dp * 2, d1 = d0 + 1;

    float a00 = 0, a01 = 0, a02 = 0, a03 = 0, a04 = 0, a05 = 0, a06 = 0, a07 = 0;
    float a10 = 0, a11 = 0, a12 = 0, a13 = 0, a14 = 0, a15 = 0, a16 = 0, a17 = 0;

    for (int hd = 0; hd < 5; hd++) {
        if (hd) __syncthreads();   // protect hl/al overwrite
        for (int e = t; e < 288; e += 192) {
            const int row = e >> 3, col = (e & 7) * 8;
            *(uint4*)&hl[row * 64 + col] =
                *(const uint4*)&h[(size_t)(nb + row) * 2560 + hd * 512 + cb + col];
        }
        const float4* ap = (const float4*)(alphaG + ((size_t)b * 5 + hd) * 1296);
        for (int e = t; e < 324; e += 192) ((float4*)al)[e] = ap[e];
        __syncthreads();
        if (t < 144) {
            const float* ar0 = &al[d0 * 36];
            const float* ar1 = &al[d1 * 36];
            #pragma unroll
            for (int s = 0; s < 36; s++) {
                const uint4 hv = *(const uint4*)&hl[s * 64 + c8];
                const float f0 = b2f((u16)hv.x), f1 = b2f((u16)(hv.x >> 16));
                const float f2 = b2f((u16)hv.y), f3 = b2f((u16)(hv.y >> 16));
                const float f4 = b2f((u16)hv.z), f5 = b2f((u16)(hv.z >> 16));
                const float f6 = b2f((u16)hv.w), f7 = b2f((u16)(hv.w >> 16));
                const float av0 = ar0[s], av1 = ar1[s];
                a00 += av0 * f0; a01 += av0 * f1; a02 += av0 * f2; a03 += av0 * f3;
                a04 += av0 * f4; a05 += av0 * f5; a06 += av0 * f6; a07 += av0 * f7;
                a10 += av1 * f0; a11 += av1 * f1; a12 += av1 * f2; a13 += av1 * f3;
                a14 += av1 * f4; a15 += av1 * f5; a16 += av1 * f6; a17 += av1 * f7;
            }
        }
    }
    if (t < 144) {
        const float* bp = &bias3[cb + c8];
        const float b0 = bp[0], b1 = bp[1], b2 = bp[2], b3v = bp[3];
        const float b4 = bp[4], b5 = bp[5], b6 = bp[6], b7 = bp[7];
        float* op0 = &outp[(size_t)(nb + d0) * 512 + cb + c8];
        float* op1 = &outp[(size_t)(nb + d1) * 512 + cb + c8];
        float4 w;
        w.x = a00 + b0; w.y = a01 + b1; w.z = a02 + b2; w.w = a03 + b3v;
        *(float4*)op0 = w;
        w.x = a04 + b4; w.y = a05 + b5; w.z = a06 + b6; w.w = a07 + b7;
        *(float4*)(op0 + 4) = w;
        w.x = a10 + b0; w.y = a11 + b1; w.z = a12 + b2; w.w = a13 + b3v;
        *(float4*)op1 = w;
        w.x = a14 + b4; w.y = a15 + b5; w.z = a16 + b6; w.w = a17 + b7;
        *(float4*)(op1 + 4) = w;
    }
}

// ---------------------------------------------------------------------------
// Workspace ~73.5 MB, lifetime-packed:
//  E: qe_c 0.66M | of_c 18.87M
//  A (23.59M): WqT(10.49)+qpart(10.49 @ +10.49, splitK=10) -> x -> g1 -> h3
//  B ( 9.44M): WvT(8.39), q(1.05 @ +8.39) -> g2
//  C ( 9.44M): h1 -> h2
//  F ( 5.24M): W3T (S0 -> S11 read)  then  alphaG (S13 -> S14)   [union]
//  G ( 6.29M): W1T(4.19) + W2T(2.10)  (S0 -> S8 read)
// ---------------------------------------------------------------------------
extern "C" void kernel_launch(void* const* d_in, const int* in_sizes, int n_in,
                              void* d_out, int out_size, void* d_ws, size_t ws_size,
                              hipStream_t stream)
{
    const float* qe  = (const float*)d_in[0];    // [128,2400]
    const float* of  = (const float*)d_in[1];    // [4608,2048]
    const float* Wq  = (const float*)d_in[3];    // [2400,2048]
    const float* bq  = (const float*)d_in[4];
    const float* Wv  = (const float*)d_in[5];    // [2048,2048]
    const float* bv  = (const float*)d_in[6];
    const float* W1  = (const float*)d_in[7];    // [2048,1024]
    const float* a1s = (const float*)d_in[8];
    const float* a1d = (const float*)d_in[9];
    const float* b1  = (const float*)d_in[10];
    const float* W2  = (const float*)d_in[11];   // [1024,1024]
    const float* a2s = (const float*)d_in[12];
    const float* a2d = (const float*)d_in[13];
    const float* b2  = (const float*)d_in[14];
    const float* W3  = (const float*)d_in[15];   // [1024,2560]
    const float* a3s = (const float*)d_in[16];
    const float* a3d = (const float*)d_in[17];
    const float* b3  = (const float*)d_in[18];
    float* out = (float*)d_out;
    (void)ws_size; (void)in_sizes; (void)n_in; (void)out_size;

    char* W0 = (char*)d_ws;
    size_t off = 0;
    auto alloc = [&](size_t bytes) -> char* {
        char* p = W0 + off; off += (bytes + 255) & ~(size_t)255; return p;
    };
    u16* qe_c = (u16*)alloc(128ull * 2560 * 2);
    u16* of_c = (u16*)alloc(4608ull * 2048 * 2);
    const size_t szA = 4608ull * 2560 * 2;
    const size_t szB = 4608ull * 1024 * 2;
    const size_t szC = 4608ull * 1024 * 2;
    char* Abase = alloc(szA);
    char* Bbase = alloc(szB);
    char* Cbase = alloc(szC);
    char* Fbase = alloc(2560ull * 1024 * 2);   // 5.24 MB union: W3T then alphaG
    char* Gbase = alloc(1024ull * 2048 * 2 + 1024ull * 1024 * 2);  // W1T + W2T

    u16*   WqT   = (u16*)Abase;                           // [2048,2560]
    float* qpart = (float*)(Abase + 2048ull * 2560 * 2);  // 10 x 1.05 MB (splitK=10)
    u16*   x     = (u16*)Abase;
    u16*   g1    = (u16*)Abase;
    u16*   h3    = (u16*)Abase;
    u16*   WvT   = (u16*)Bbase;                           // [2048,2048]
    float* q     = (float*)(Bbase + 2048ull * 2048 * 2);
    u16*   g2    = (u16*)Bbase;
    u16*   h1    = (u16*)Cbase;
    u16*   h2    = (u16*)Cbase;
    u16*   W3T   = (u16*)Fbase;                           // [2560,1024], S0->S11
    float* alphaG = (float*)Fbase;                        // 3.32 MB, S13->S14
    u16*   W1T   = (u16*)Gbase;                           // [1024,2048]
    u16*   W2T   = (u16*)(Gbase + 1024ull * 2048 * 2);    // [1024,1024]

    // S0: ALL converts + ALL weight transposes in ONE launch
    prep_all<<<dim3(14208), 256, 0, stream>>>(of, of_c, qe, qe_c,
                                              Wq, WqT, Wv, WvT, W3, W3T,
                                              W1, W1T, W2, W2T);

    // S2-S3: q = qe @ Wq + bq   (splitK=10 x 256: 160 blocks)
    gemm_tn<1, 128><<<dim3(16, 1, 10), 256, 0, stream>>>(qe_c, WqT, 128, 2048, 2560, 256,
                                                         qpart, nullptr, nullptr, nullptr);
    qcombine<<<dim3(128 * 2048 / 256), 256, 0, stream>>>(qpart, bq, q, 128 * 2048, 10);

    // S4: x = (of @ Wv + bv) * q_rep   (576 blocks — frozen best)
    gemm_tn<2, 128><<<dim3(16, 36, 1), 256, 0, stream>>>(of_c, WvT, 4608, 2048, 2048, 2048,
                                                         nullptr, x, bv, q);

    // S6-S7: layer 1   (BM=64 -> 576 blocks, r15 confirmed)
    gemm_tn<0, 64><<<dim3(8, 72, 1), 256, 0, stream>>>(x, W1T, 4608, 1024, 2048, 2048,
                                                       nullptr, h1, nullptr, nullptr);
    attn_kernel<4, 256, 1><<<dim3(4, B_IMG), 256, 0, stream>>>(h1, a1s, a1d, b1, nullptr, g1);

    // S8-S9: layer 2 (+ residual g1)   (BM=64 -> 576 blocks)
    gemm_tn<0, 64><<<dim3(8, 72, 1), 256, 0, stream>>>(g1, W2T, 4608, 1024, 1024, 1024,
                                                       nullptr, h2, nullptr, nullptr);
    attn_kernel<4, 256, 2><<<dim3(4, B_IMG), 256, 0, stream>>>(h2, a2s, a2d, b2, g1, g2);

    // S11-S14: layer 3 (5 heads, mean + b3) -> fp32 out   (BM=128, 720 blocks)
    gemm_tn<0, 128><<<dim3(20, 36, 1), 256, 0, stream>>>(g2, W3T, 4608, 2560, 1024, 1024,
                                                         nullptr, h3, nullptr, nullptr);
    al_alpha<5, 512, true><<<dim3(5, B_IMG), 256, 0, stream>>>(h3, a3s, a3d, alphaG);
    attn_agg_mean<<<dim3(8, B_IMG), 192, 0, stream>>>(h3, alphaG, b3, out);
}